// Round 6
// baseline (664.877 us; speedup 1.0000x reference)
//
#include <hip/hip_runtime.h>
#include <math.h>

#define E_EDGES 100000

typedef unsigned short u16;
typedef unsigned int u32;

using bfrag = __attribute__((ext_vector_type(8))) short;
using ffrag = __attribute__((ext_vector_type(4))) float;

__device__ inline float bf2f(u32 u) { union { u32 i; float f; } c; c.i = u << 16; return c.f; }
__device__ inline u16 f2bf(float f) {
  union { u32 i; float f; } c; c.f = f;
  u32 u = c.i;
  return (u16)((u + 0x7FFFu + ((u >> 16) & 1u)) >> 16);
}

// ---------------- structs ----------------
struct CsrArgs { int relid[24]; int lay[24]; int nd[24]; int rpoff[24];
                 int bkoff[24]; int bboff[24]; int nb[24]; };

struct AggAllArgs {
  const u16* xsrc[18];
  const int* rowptr[18];
  const int* esrc[18];
  u16* dst[18];
  int nd[18]; int pitch[18]; int koff[18];
};

struct WTStackArgs {
  int srcrel[23]; int grp[23]; long outoff[23]; int koff[23]; int pitch[23];
  int gnr[5]; int grel[5][6];
};

struct WTArgs { const float* W[15]; u16* out[15]; int K[15]; int N[15]; int Kpad[15]; };
struct PadArgs { const float* src[11]; u16* dst[11]; int K[11]; int Kpad8[11];
                 int total[11]; int aligned[11]; };
struct InLinBArgs { const u16* A[5]; const u16* WT[5]; const float* bias[5]; u16* C[5];
                    int M[5]; int Kpad[5]; };
struct FusedArgs {
  const u16* A[5]; const u16* selfA[5]; const u16* WTC[5]; const float* biasC[5];
  const u16* W1[5]; const float* b1[5]; const u16* W2[5]; const float* b2[5];
  const int* POS[5]; u16* C[5]; int M[5]; int kself[5]; int Kpad[5];
};
struct PosArgs { const int* m0[5]; const int* m1[5]; int* pos[5]; int n[5]; };
struct HeadArgs { const u16* WT[2]; const float* b1[2]; float* hid[2]; const u16* A; int M; };
struct HeadRArgs { const float* hid[2]; const float* w2[2]; const float* b2[2]; float* out; int M; };

// ---------------- batched bf16 GEMM (input linears), N=128 ------------
__global__ __launch_bounds__(256) void tgemm_inb(InLinBArgs a)
{
  const int z = blockIdx.z;
  const int M = a.M[z], Kpad = a.Kpad[z];
  const int rowbase = blockIdx.x * 64;
  if (rowbase >= M) return;
  __shared__ u16 sA[64 * 40];
  __shared__ u16 sB[128 * 40];
  const int tid = threadIdx.x;
  const int w = tid >> 6, lane = tid & 63;
  const int quad = lane >> 4, m = lane & 15;
  const int sr = tid >> 2, sc = tid & 3;
  const int br = tid >> 1, bh = tid & 1;
  const u16* A = a.A[z];
  const u16* WT = a.WT[z];
  ffrag acc[8];
  #pragma unroll
  for (int i = 0; i < 8; i++) { acc[i][0] = 0.f; acc[i][1] = 0.f; acc[i][2] = 0.f; acc[i][3] = 0.f; }

  for (int kt = 0; kt < Kpad / 32; kt++) {
    int gr = rowbase + sr, gk = kt * 32 + sc * 8;
    uint4 st = make_uint4(0, 0, 0, 0);
    if (gr < M) st = *(const uint4*)(A + (long)gr * Kpad + gk);
    const u16* wrow = WT + (long)br * Kpad + kt * 32 + bh * 16;
    uint4 b0 = *(const uint4*)wrow;
    uint4 b1 = *(const uint4*)(wrow + 8);

    if (kt) __syncthreads();
    *(uint4*)&sA[sr * 40 + sc * 8] = st;
    *(uint4*)&sB[br * 40 + bh * 16] = b0;
    *(uint4*)&sB[br * 40 + bh * 16 + 8] = b1;
    __syncthreads();

    bfrag av = *(const bfrag*)&sA[(w * 16 + m) * 40 + quad * 8];
    #pragma unroll
    for (int ct = 0; ct < 8; ct++) {
      bfrag bv = *(const bfrag*)&sB[(ct * 16 + m) * 40 + quad * 8];
      acc[ct] = __builtin_amdgcn_mfma_f32_16x16x32_bf16(av, bv, acc[ct], 0, 0, 0);
    }
  }

  const float* bias = a.bias[z];
  u16* C = a.C[z];
  #pragma unroll
  for (int ct = 0; ct < 8; ct++) {
    int col = ct * 16 + m;
    float bv = bias[col];
    #pragma unroll
    for (int r = 0; r < 4; r++) {
      int row = rowbase + w * 16 + quad * 4 + r;
      if (row < M) C[(long)row * 128 + col] = f2bf(acc[ct][r] + bv);
    }
  }
}

// ------- fused conv + MLP1(relu) + MLP2 + POS-scatter, direct-load edition ----------
// A/B fragments loaded straight from global (weights L2-hot, A rows contiguous).
// LDS only holds the two inter-stage transposes (m1, m2; stride 152 u16 = 12 mod 32
// words -> distinct bank slots per m). 4 barriers per block total.
#define MSTR 152
__global__ __launch_bounds__(256) void fused_mlp(FusedArgs a)
{
  const int z = blockIdx.z;
  const int M = a.M[z];
  const int rowbase = blockIdx.x * 64;
  if (rowbase >= M) return;
  __shared__ u16 LDS[2 * 64 * MSTR];
  u16* m1 = LDS;
  u16* m2 = LDS + 64 * MSTR;
  const int tid = threadIdx.x;
  const int w = tid >> 6, lane = tid & 63;
  const int quad = lane >> 4, m = lane & 15;
  const int kself = a.kself[z], Kpad = a.Kpad[z];
  const u16* A = a.A[z];
  const u16* selfA = a.selfA[z];
  const int arow = rowbase + w * 16 + m;      // A-fragment row for this lane
  const int orow = w * 16 + quad * 4;          // output sub-row base (within tile)

  // ---- stage 1: conv (direct a from A/selfA, direct b from WTC) ----
  {
    const u16* WT = a.WTC[z];
    ffrag acc[8];
    #pragma unroll
    for (int i = 0; i < 8; i++) { acc[i][0] = 0.f; acc[i][1] = 0.f; acc[i][2] = 0.f; acc[i][3] = 0.f; }
    for (int kt = 0; kt < Kpad / 32; kt++) {
      int gk = kt * 32 + quad * 8;
      bfrag av;
      if (arow < M) {
        const u16* src = (gk < kself) ? (A + (long)arow * kself + gk)
                                      : (selfA + (long)arow * 128 + (gk - kself));
        av = *(const bfrag*)src;
      } else {
        av = bfrag{0,0,0,0,0,0,0,0};
      }
      #pragma unroll
      for (int ct = 0; ct < 8; ct++) {
        bfrag bv = *(const bfrag*)(WT + (long)(ct * 16 + m) * Kpad + gk);
        acc[ct] = __builtin_amdgcn_mfma_f32_16x16x32_bf16(av, bv, acc[ct], 0, 0, 0);
      }
    }
    const float* bc = a.biasC[z];
    #pragma unroll
    for (int ct = 0; ct < 8; ct++) {
      int col = ct * 16 + m;
      float bv = bc[col];
      #pragma unroll
      for (int r = 0; r < 4; r++)
        m1[(orow + r) * MSTR + col] = f2bf(acc[ct][r] + bv);
    }
  }
  __syncthreads();   // m1 visible

  // ---- stages 2+3 interleaved: per K-half h, mlp1-half -> m2 -> mlp2 partial ----
  ffrag acc2[8];
  #pragma unroll
  for (int i = 0; i < 8; i++) { acc2[i][0] = 0.f; acc2[i][1] = 0.f; acc2[i][2] = 0.f; acc2[i][3] = 0.f; }
  {
    const u16* W1 = a.W1[z];
    const u16* W2 = a.W2[z];
    const float* b1p = a.b1[z];
    for (int h = 0; h < 2; h++) {
      ffrag acch[8];
      #pragma unroll
      for (int i = 0; i < 8; i++) { acch[i][0] = 0.f; acch[i][1] = 0.f; acch[i][2] = 0.f; acch[i][3] = 0.f; }
      for (int kt = 0; kt < 4; kt++) {
        bfrag av = *(const bfrag*)&m1[(w * 16 + m) * MSTR + kt * 32 + quad * 8];
        #pragma unroll
        for (int ct = 0; ct < 8; ct++) {
          bfrag bv = *(const bfrag*)(W1 + (long)(h * 128 + ct * 16 + m) * 128 + kt * 32 + quad * 8);
          acch[ct] = __builtin_amdgcn_mfma_f32_16x16x32_bf16(av, bv, acch[ct], 0, 0, 0);
        }
      }
      if (h) __syncthreads();                // prior m2 readers done before overwrite
      #pragma unroll
      for (int ct = 0; ct < 8; ct++) {
        int col = ct * 16 + m;
        float bv = b1p[h * 128 + col];
        #pragma unroll
        for (int r = 0; r < 4; r++)
          m2[(orow + r) * MSTR + col] = f2bf(fmaxf(acch[ct][r] + bv, 0.f));
      }
      __syncthreads();                       // m2 visible
      for (int kt2 = 0; kt2 < 4; kt2++) {
        bfrag av = *(const bfrag*)&m2[(w * 16 + m) * MSTR + kt2 * 32 + quad * 8];
        #pragma unroll
        for (int ct = 0; ct < 8; ct++) {
          bfrag bv = *(const bfrag*)(W2 + (long)(ct * 16 + m) * 256 + h * 128 + kt2 * 32 + quad * 8);
          acc2[ct] = __builtin_amdgcn_mfma_f32_16x16x32_bf16(av, bv, acc2[ct], 0, 0, 0);
        }
      }
    }
  }

  // ---- epilogue: bias + POS scatter ----
  {
    const int* POS = a.POS[z];
    const float* b2p = a.b2[z];
    u16* C = a.C[z];
    #pragma unroll
    for (int ct = 0; ct < 8; ct++) {
      int col = ct * 16 + m;
      float bv = b2p[col];
      #pragma unroll
      for (int r = 0; r < 4; r++) {
        int row = rowbase + orow + r;
        if (row < M) {
          int j = POS[row];
          if (j >= 0) C[(long)j * 128 + col] = f2bf(acc2[ct][r] + bv);
        }
      }
    }
  }
}

// ---------------- L1 gene conv: gathered A + direct self, bf16 out ----------------
__global__ __launch_bounds__(256) void conv_l1(const u16* __restrict__ A,
                                               const u16* __restrict__ selfA,
                                               const u16* __restrict__ WT,
                                               const float* __restrict__ bias,
                                               u16* __restrict__ C,
                                               int M, int kself, int Kpad)
{
  const int rowbase = blockIdx.x * 64;
  if (rowbase >= M) return;
  __shared__ u16 sA[64 * 40];
  __shared__ u16 sB[128 * 40];
  const int tid = threadIdx.x;
  const int w = tid >> 6, lane = tid & 63;
  const int quad = lane >> 4, m = lane & 15;
  const int sr = tid >> 2, sc = tid & 3;
  const int br = tid >> 1, bh = tid & 1;
  ffrag acc[8];
  #pragma unroll
  for (int i = 0; i < 8; i++) { acc[i][0] = 0.f; acc[i][1] = 0.f; acc[i][2] = 0.f; acc[i][3] = 0.f; }

  for (int kt = 0; kt < Kpad / 32; kt++) {
    int gr = rowbase + sr, gk = kt * 32 + sc * 8;
    uint4 st = make_uint4(0, 0, 0, 0);
    if (gr < M) {
      const u16* src = (gk < kself) ? (A + (long)gr * kself + gk)
                                    : (selfA + (long)gr * 128 + (gk - kself));
      st = *(const uint4*)src;
    }
    const u16* wrow = WT + (long)br * Kpad + kt * 32 + bh * 16;
    uint4 b0 = *(const uint4*)wrow;
    uint4 b1 = *(const uint4*)(wrow + 8);

    if (kt) __syncthreads();
    *(uint4*)&sA[sr * 40 + sc * 8] = st;
    *(uint4*)&sB[br * 40 + bh * 16] = b0;
    *(uint4*)&sB[br * 40 + bh * 16 + 8] = b1;
    __syncthreads();

    bfrag av = *(const bfrag*)&sA[(w * 16 + m) * 40 + quad * 8];
    #pragma unroll
    for (int ct = 0; ct < 8; ct++) {
      bfrag bv = *(const bfrag*)&sB[(ct * 16 + m) * 40 + quad * 8];
      acc[ct] = __builtin_amdgcn_mfma_f32_16x16x32_bf16(av, bv, acc[ct], 0, 0, 0);
    }
  }

  #pragma unroll
  for (int ct = 0; ct < 8; ct++) {
    int col = ct * 16 + m;
    float bv = bias[col];
    #pragma unroll
    for (int r = 0; r < 4; r++) {
      int row = rowbase + w * 16 + quad * 4 + r;
      if (row < M) C[(long)row * 128 + col] = f2bf(acc[ct][r] + bv);
    }
  }
}

// ---------------- streaming fp32 -> padded bf16 convert (11 slots, one launch) -------
__global__ __launch_bounds__(256) void padcvt_kernel(PadArgs a)
{
  const int z = blockIdx.y;
  int idx = blockIdx.x * 256 + threadIdx.x;
  if (idx >= a.total[z]) return;
  const int kp8 = a.Kpad8[z];
  const int K = a.K[z];
  int row = idx / kp8;
  int c8 = idx - row * kp8;
  int base = c8 * 8;
  u32 wv[4];
  if (a.aligned[z]) {
    const float4* src = (const float4*)(a.src[z] + (long)row * K + base);
    float4 f0 = src[0];
    float4 f1 = src[1];
    wv[0] = (u32)f2bf(f0.x) | ((u32)f2bf(f0.y) << 16);
    wv[1] = (u32)f2bf(f0.z) | ((u32)f2bf(f0.w) << 16);
    wv[2] = (u32)f2bf(f1.x) | ((u32)f2bf(f1.y) << 16);
    wv[3] = (u32)f2bf(f1.z) | ((u32)f2bf(f1.w) << 16);
  } else {
    const float* src = a.src[z] + (long)row * K + base;
    #pragma unroll
    for (int i = 0; i < 4; i++) {
      float lo = (base + 2 * i     < K) ? src[2 * i]     : 0.f;
      float hi = (base + 2 * i + 1 < K) ? src[2 * i + 1] : 0.f;
      wv[i] = (u32)f2bf(lo) | ((u32)f2bf(hi) << 16);
    }
  }
  *(uint4*)(a.dst[z] + (long)row * (kp8 * 8) + base) = make_uint4(wv[0], wv[1], wv[2], wv[3]);
}

// ---------------- batched gene heads (bf16 A, fp32 out, relu, N=256) ----------------
__global__ __launch_bounds__(256) void tgemm_head(HeadArgs a)
{
  const int z = blockIdx.z;
  const int M = a.M;
  const int rowbase = blockIdx.x * 64;
  const int colbase = blockIdx.y * 128;
  __shared__ u16 sA[64 * 40];
  __shared__ u16 sB[128 * 40];
  const int tid = threadIdx.x;
  const int w = tid >> 6, lane = tid & 63;
  const int quad = lane >> 4, m = lane & 15;
  const int sr = tid >> 2, sc = tid & 3;
  const int br = tid >> 1, bh = tid & 1;
  const u16* A = a.A;
  const u16* WT = a.WT[z];
  ffrag acc[8];
  #pragma unroll
  for (int i = 0; i < 8; i++) { acc[i][0] = 0.f; acc[i][1] = 0.f; acc[i][2] = 0.f; acc[i][3] = 0.f; }

  for (int kt = 0; kt < 4; kt++) {
    int gr = rowbase + sr, gk = kt * 32 + sc * 8;
    uint4 st = make_uint4(0, 0, 0, 0);
    if (gr < M) st = *(const uint4*)(A + (long)gr * 128 + gk);
    const u16* wrow = WT + (long)(colbase + br) * 128 + kt * 32 + bh * 16;
    uint4 b0 = *(const uint4*)wrow;
    uint4 b1 = *(const uint4*)(wrow + 8);

    if (kt) __syncthreads();
    *(uint4*)&sA[sr * 40 + sc * 8] = st;
    *(uint4*)&sB[br * 40 + bh * 16] = b0;
    *(uint4*)&sB[br * 40 + bh * 16 + 8] = b1;
    __syncthreads();

    bfrag av = *(const bfrag*)&sA[(w * 16 + m) * 40 + quad * 8];
    #pragma unroll
    for (int ct = 0; ct < 8; ct++) {
      bfrag bv = *(const bfrag*)&sB[(ct * 16 + m) * 40 + quad * 8];
      acc[ct] = __builtin_amdgcn_mfma_f32_16x16x32_bf16(av, bv, acc[ct], 0, 0, 0);
    }
  }

  const float* bias = a.b1[z];
  float* C = a.hid[z];
  #pragma unroll
  for (int ct = 0; ct < 8; ct++) {
    int col = colbase + ct * 16 + m;
    float bv = bias[col];
    #pragma unroll
    for (int r = 0; r < 4; r++) {
      int row = rowbase + w * 16 + quad * 4 + r;
      if (row < M) C[(long)row * 256 + col] = fmaxf(acc[ct][r] + bv, 0.f);
    }
  }
}

// ---------------- CSR build: bucket-level histogram (LDS-privatized) ----------------
__global__ __launch_bounds__(256) void bhist_kernel(const int* __restrict__ e0,
                                                    const int* __restrict__ e1,
                                                    int* __restrict__ bcnt, CsrArgs a)
{
  const int slot = blockIdx.x / 25;
  const int ch = blockIdx.x % 25;
  const int base = ch * 4096;
  const int n = (E_EDGES - base < 4096) ? (E_EDGES - base) : 4096;
  const int* E = a.lay[slot] ? e1 : e0;
  const int r = a.relid[slot];
  const int tid = threadIdx.x;
  __shared__ int h[256];
  h[tid] = 0;
  __syncthreads();
  const int* darr = E + (r * 2 + 1) * E_EDGES + base;
  for (int i = tid; i < n; i += 256) atomicAdd(&h[darr[i] >> 7], 1);
  __syncthreads();
  if (tid < a.nb[slot] && h[tid]) atomicAdd(&bcnt[a.bkoff[slot] + tid], h[tid]);
}

// per-slot scan of bucket counts -> bucket bases (exclusive, + sentinel) and cursors
__global__ __launch_bounds__(256) void bscan_kernel(const int* __restrict__ bcnt,
                                                    int* __restrict__ bbase,
                                                    int* __restrict__ bcur, CsrArgs a)
{
  int slot = blockIdx.x;
  int nb = a.nb[slot];
  int tid = threadIdx.x, lane = tid & 63, w = tid >> 6;
  __shared__ int ws[4];
  int v = (tid < nb) ? bcnt[a.bkoff[slot] + tid] : 0;
  int si = v;
  #pragma unroll
  for (int off = 1; off < 64; off <<= 1) {
    int t = __shfl_up(si, off, 64);
    if (lane >= off) si += t;
  }
  if (lane == 63) ws[w] = si;
  __syncthreads();
  int woff = 0;
  #pragma unroll
  for (int k = 0; k < 4; k++) if (k < w) woff += ws[k];
  int excl = woff + si - v;
  if (tid < nb) { bbase[a.bboff[slot] + tid] = excl; bcur[a.bkoff[slot] + tid] = excl; }
  if (tid == 0) bbase[a.bboff[slot] + nb] = ws[0] + ws[1] + ws[2] + ws[3];
}

// pass B: per-block LDS bucketing + coalesced burst append into TMP
__global__ __launch_bounds__(256) void bucket_scatter(const int* __restrict__ e0,
                                                      const int* __restrict__ e1,
                                                      int* __restrict__ bcur,
                                                      u32* __restrict__ tmp, CsrArgs a)
{
  const int slot = blockIdx.x / 25;
  const int ch = blockIdx.x % 25;
  const int base = ch * 4096;
  const int n = (E_EDGES - base < 4096) ? (E_EDGES - base) : 4096;
  const int* E = a.lay[slot] ? e1 : e0;
  const int r = a.relid[slot];
  const int nb = a.nb[slot];
  const int tid = threadIdx.x;
  __shared__ int hist[256], start[256], gbase[256], lcur[256];
  __shared__ u32 sorted[4096];
  hist[tid] = 0;
  __syncthreads();
  const int* darr = E + (r * 2 + 1) * E_EDGES + base;
  const int* sarr = E + r * 2 * E_EDGES + base;
  for (int i = tid; i < n; i += 256) atomicAdd(&hist[darr[i] >> 7], 1);
  __syncthreads();
  if (tid == 0) {
    int s = 0;
    for (int b = 0; b < nb; b++) { start[b] = s; s += hist[b]; }
  }
  __syncthreads();
  if (tid < nb) {
    gbase[tid] = atomicAdd(&bcur[a.bkoff[slot] + tid], hist[tid]);
    lcur[tid] = start[tid];
  }
  __syncthreads();
  for (int i = tid; i < n; i += 256) {
    int dst = darr[i], src = sarr[i];
    int pos = atomicAdd(&lcur[dst >> 7], 1);
    sorted[pos] = ((u32)dst << 16) | (u32)src;
  }
  __syncthreads();
  u32* out = tmp + (long)slot * E_EDGES;
  for (int i = tid; i < n; i += 256) {
    u32 p = sorted[i];
    int b = p >> 23;
    out[gbase[b] + (i - start[b])] = p;
  }
}

// pass C: per-(slot,bucket): derive rowptr segment + LDS counting-sort into CSR
__global__ __launch_bounds__(256) void bucket_to_csr(const u32* __restrict__ tmp,
                                                     const int* __restrict__ bbase,
                                                     int* __restrict__ rp,
                                                     int* __restrict__ esrc, CsrArgs a)
{
  const int b = blockIdx.x, slot = blockIdx.y;
  if (b >= a.nb[slot]) return;
  const int rb = a.rpoff[slot];
  const int bb = bbase[a.bboff[slot] + b];
  const int be = bbase[a.bboff[slot] + b + 1];
  const int cnt = be - bb;
  const int rowlo = b << 7;
  int rowhi = rowlo + 128; if (rowhi > a.nd[slot]) rowhi = a.nd[slot];
  const int nrow = rowhi - rowlo;
  const int tid = threadIdx.x;
  __shared__ int rcnt[128];
  __shared__ int rpref[129];
  __shared__ int scur[128];
  __shared__ u32 sbuf[8192];
  if (tid < 128) rcnt[tid] = 0;
  __syncthreads();
  const u32* in = tmp + (long)slot * E_EDGES + bb;
  for (int i = tid; i < cnt; i += 256) atomicAdd(&rcnt[(in[i] >> 16) & 127], 1);
  __syncthreads();
  if (tid == 0) {
    int s = 0;
    for (int t = 0; t < 128; t++) { rpref[t] = s; s += rcnt[t]; }
    rpref[128] = s;
  }
  __syncthreads();
  if (tid < nrow) rp[rb + rowlo + tid] = bb + rpref[tid];
  if (tid == 0) rp[rb + rowhi] = be;
  if (tid < 128) scur[tid] = rpref[tid];
  __syncthreads();
  int* out = esrc + (long)slot * E_EDGES + bb;
  if (cnt <= 8192) {
    for (int i = tid; i < cnt; i += 256) {
      u32 p = in[i];
      int pos = atomicAdd(&scur[(p >> 16) & 127], 1);
      sbuf[pos] = p & 0xFFFFu;
    }
    __syncthreads();
    for (int i = tid; i < cnt; i += 256) out[i] = (int)sbuf[i];
  } else {
    for (int i = tid; i < cnt; i += 256) {
      u32 p = in[i];
      int pos = atomicAdd(&scur[(p >> 16) & 127], 1);
      out[pos] = (int)(p & 0xFFFFu);
    }
  }
}

// ---------------- weight prep ----------------
__global__ __launch_bounds__(256) void wtstack_kernel(const float* __restrict__ wl,
                                                      const float* __restrict__ wr,
                                                      const float* __restrict__ bl,
                                                      u16* __restrict__ WTG,
                                                      float* __restrict__ BLS, WTStackArgs a)
{
  int slot = blockIdx.y;
  int t = blockIdx.x * 256 + threadIdx.x;
  int krel = t & 127, n = t >> 7;
  int sr = a.srcrel[slot];
  float v;
  if (sr >= 0) {
    v = wl[(long)sr * 16384 + krel * 128 + n];
  } else {
    int g = a.grp[slot];
    v = 0.f;
    for (int i = 0; i < a.gnr[g]; i++) v += wr[(long)a.grel[g][i] * 16384 + krel * 128 + n];
    if (t < 128) {
      float b = 0.f;
      for (int i = 0; i < a.gnr[g]; i++) b += bl[a.grel[g][i] * 128 + t];
      BLS[g * 128 + t] = b;
    }
  }
  WTG[a.outoff[slot] + (long)n * a.pitch[slot] + a.koff[slot] + krel] = f2bf(v);
}

__global__ __launch_bounds__(256) void wt_kernel(WTArgs a)
{
  int s = blockIdx.y;
  int idx = blockIdx.x * 256 + threadIdx.x;
  int K = a.K[s], N = a.N[s], Kpad = a.Kpad[s];
  if (idx >= N * Kpad) return;
  int n = idx / Kpad, k = idx - n * Kpad;
  a.out[s][idx] = (k < K) ? f2bf(a.W[s][(long)k * N + n]) : (u16)0;
}

__global__ __launch_bounds__(256) void pos_kernel(PosArgs a)
{
  int g = blockIdx.y;
  int i = blockIdx.x * 256 + threadIdx.x;
  if (i >= a.n[g]) return;
  int key = a.m0[g][i];
  const int* m1 = a.m1[g];
  int lo = 0, hi = a.n[g] - 1, pos = -1;
  while (lo <= hi) {
    int mid = (lo + hi) >> 1;
    int v = m1[mid];
    if (v == key) { pos = mid; break; }
    if (v < key) lo = mid + 1; else hi = mid - 1;
  }
  a.pos[g][i] = pos;
}

// ---------------- aggregation: 16 lanes/row, dwordx4 gathers, 4-deep unroll ---------
__global__ __launch_bounds__(256) void agg_all(AggAllArgs a)
{
  int slot = blockIdx.y;
  int grp = threadIdx.x >> 4;
  int lane = threadIdx.x & 15;
  int row = blockIdx.x * 16 + grp;
  if (row >= a.nd[slot]) return;
  u16* dst = a.dst[slot] + (long)row * a.pitch[slot] + a.koff[slot] + lane * 8;
  const uint4* x4 = (const uint4*)a.xsrc[slot];
  const int* rp = a.rowptr[slot];
  int c0 = rp[row], c1 = rp[row + 1];
  const int* es = a.esrc[slot];
  float acc[8];
  #pragma unroll
  for (int i = 0; i < 8; i++) acc[i] = 0.f;
  int e = c0;
  for (; e + 4 <= c1; e += 4) {
    int s0 = es[e], s1 = es[e + 1], s2 = es[e + 2], s3 = es[e + 3];
    uint4 v0 = x4[(long)s0 * 16 + lane];
    uint4 v1 = x4[(long)s1 * 16 + lane];
    uint4 v2 = x4[(long)s2 * 16 + lane];
    uint4 v3 = x4[(long)s3 * 16 + lane];
    const u32* w0 = (const u32*)&v0;
    const u32* w1 = (const u32*)&v1;
    const u32* w2 = (const u32*)&v2;
    const u32* w3 = (const u32*)&v3;
    #pragma unroll
    for (int i = 0; i < 4; i++) {
      acc[2*i]   += bf2f(w0[i] & 0xFFFF) + bf2f(w1[i] & 0xFFFF)
                  + bf2f(w2[i] & 0xFFFF) + bf2f(w3[i] & 0xFFFF);
      acc[2*i+1] += bf2f(w0[i] >> 16) + bf2f(w1[i] >> 16)
                  + bf2f(w2[i] >> 16) + bf2f(w3[i] >> 16);
    }
  }
  for (; e < c1; e++) {
    uint4 v = x4[(long)es[e] * 16 + lane];
    const u32* wv = (const u32*)&v;
    #pragma unroll
    for (int i = 0; i < 4; i++) {
      acc[2*i]   += bf2f(wv[i] & 0xFFFF);
      acc[2*i+1] += bf2f(wv[i] >> 16);
    }
  }
  int c = c1 - c0;
  float inv = 1.f / (float)(c > 1 ? c : 1);
  u32 o[4];
  #pragma unroll
  for (int i = 0; i < 4; i++)
    o[i] = (u32)f2bf(acc[2*i] * inv) | ((u32)f2bf(acc[2*i+1] * inv) << 16);
  *(uint4*)dst = make_uint4(o[0], o[1], o[2], o[3]);
}

// ---------------- batched head reduce (4 rows/block) ----------------
__global__ __launch_bounds__(256) void head_reduce2(HeadRArgs a)
{
  int wave = threadIdx.x >> 6, lane = threadIdx.x & 63;
  int row = blockIdx.x * 4 + wave;
  int z = blockIdx.y;
  if (row >= a.M) return;
  const float* h = a.hid[z] + (long)row * 256;
  const float* w2 = a.w2[z];
  float s = h[lane] * w2[lane] + h[lane + 64] * w2[lane + 64]
          + h[lane + 128] * w2[lane + 128] + h[lane + 192] * w2[lane + 192];
  #pragma unroll
  for (int off = 32; off >= 1; off >>= 1) s += __shfl_down(s, off, 64);
  if (lane == 0) {
    float v = s + a.b2[z][0];
    if (z == 0) v = 1.0f / (1.0f + expf(-v));
    a.out[row * 2 + z] = v;
  }
}

// ---------------- host orchestration ----------------
extern "C" void kernel_launch(void* const* d_in, const int* in_sizes, int n_in,
                              void* d_out, int out_size, void* d_ws, size_t ws_size,
                              hipStream_t stream)
{
  static const int NT[6] = {25000, 15000, 4000, 12000, 12000, 15000};
  static const int REL_S[19] = {2,0,2,1,0,1,3,3,1,3,1,3,4,5,0,5,1,0,1};
  static const int REL_D[19] = {0,2,1,2,1,0,3,1,3,1,3,4,3,0,5,1,5,1,0};

  auto xin   = [&](int t, int L) { return (const float*)d_in[L * 13 + 2 * t]; };
  auto mapin = [&](int t, int L) { return (const int*)d_in[L * 13 + 2 * t + 1]; };
  const int* edges0 = (const int*)d_in[12];
  const int* edges1 = (const int*)d_in[25];
  const float* W_in_atac  = (const float*)d_in[26];
  const float* b_in_atac  = (const float*)d_in[27];
  const float* W_in_gene  = (const float*)d_in[28];
  const float* b_in_gene  = (const float*)d_in[29];
  const float* W_in_pname = (const float*)d_in[30];
  const float* b_in_pname = (const float*)d_in[31];
  const float* conv_wl = (const float*)d_in[32];
  const float* conv_bl = (const float*)d_in[33];
  const float* conv_wr = (const float*)d_in[34];
  const float* mlp_w1 = (const float*)d_in[35];
  const float* mlp_b1 = (const float*)d_in[36];
  const float* mlp_w2 = (const float*)d_in[37];
  const float* mlp_b2 = (const float*)d_in[38];
  const float* gd_w1 = (const float*)d_in[39];
  const float* gd_b1 = (const float*)d_in[40];
  const float* gd_w2 = (const float*)d_in[41];
  const float* gd_b2 = (const float*)d_in[42];
  const float* gv_w1 = (const float*)d_in[43];
  const float* gv_b1 = (const float*)d_in[44];
  const float* gv_w2 = (const float*)d_in[45];
  const float* gv_b2 = (const float*)d_in[46];
  float* out = (float*)d_out;

  // dst-type groups
  static const int GD[5]       = {0, 1, 2, 3, 5};
  static const int GNR[5]      = {4, 6, 2, 4, 2};
  static const int GRELS[5][6] = {{0,5,13,18,0,0},{2,4,7,9,15,17},{1,3,0,0,0,0},
                                  {6,8,10,12,0,0},{14,16,0,0,0,0}};
  static const int GPITCH[5]   = {640, 896, 384, 640, 384};  // WTG K (incl. self 128)
  static const int GPA[5]      = {512, 768, 256, 512, 256};  // gathered-only pitch

  // ---- workspace carve ----
  float* fp = (float*)d_ws;
  auto takef = [&](size_t n) { float* q = fp; fp += n; return q; };
  float* BLS  = takef(5 * 128);
  u16* bp = (u16*)fp;
  auto takeb = [&](size_t n) { u16* q = bp; bp += n; return q; };
  u16* XB0[6]; u16* XB1[6];
  XB0[0] = takeb((size_t)25000 * 128);
  XB0[1] = takeb((size_t)15000 * 128);
  XB0[2] = takeb((size_t)4000 * 128);
  XB0[3] = takeb((size_t)12000 * 128);
  XB0[4] = takeb((size_t)12000 * 128);
  XB0[5] = takeb((size_t)15000 * 128);
  XB1[0] = takeb((size_t)25000 * 128);
  XB1[1] = takeb((size_t)15000 * 128);
  XB1[2] = takeb((size_t)4000 * 128);
  XB1[3] = takeb((size_t)12000 * 128);
  XB1[4] = nullptr;
  XB1[5] = takeb((size_t)15000 * 128);
  u16* ABUF = takeb((size_t)35328000);       // per-group gathered agg (no self)
  u16* ABUFg[5];
  {
    long o = 0;
    for (int g = 0; g < 5; g++) { ABUFg[g] = ABUF + o; o += (long)NT[GD[g]] * GPA[g]; }
  }
  u16* G1B  = takeb((size_t)15000 * 128);    // L1 conv out (bf16)
  u16* WTG  = takeb(376832);
  u16* WTIA = takeb(128 * 288);
  u16* WTIG = takeb(128 * 160);
  u16* WTIP = takeb(128 * 160);
  u16* WTM1 = takeb((size_t)5 * 32768);
  u16* WTM2 = takeb((size_t)5 * 32768);
  u16* WTHD = takeb(32768);
  u16* WTHV = takeb(32768);
  uintptr_t ipa = ((uintptr_t)bp + 15) & ~(uintptr_t)15;
  int* ip = (int*)ipa;
  auto takei = [&](size_t n) { int* q = ip; ip += n; return q; };
  int* RP    = takei(366024);
  int* BCNT  = takei(4704);
  int* BBASE = takei(4728);
  int* BCUR  = takei(4704);
  int* POSB  = takei(71000);
  int* ESRC  = takei((size_t)24 * E_EDGES);
  // aliases inside ABUF (disjoint lifetimes, in-order stream):
  u32* TMP = (u32*)ABUF;                         // CSR staging (phase 3)
  float* HIDF0 = (float*)ABUF;                   // head hidden (phase 6)
  float* HIDF1 = (float*)(ABUF + (size_t)15000 * 256 * 2);
  u16* PAD[5];                                   // padded bf16 input-linear A (phase 2)
  PAD[0] = ABUF;                       // atac0  25000*288 = 7.20M
  PAD[1] = ABUF +  7200000;            // gene0  15000*160 = 2.40M
  PAD[2] = ABUF +  9600000;            // pname0 12000*160 = 1.92M
  PAD[3] = ABUF + 11520000;            // atac1  25000*288 = 7.20M
  PAD[4] = ABUF + 18720000;            // gene1  15000*160 = 2.40M (ends 21.12M < 35.3M)

  long gbaseT[5];
  {
    long o = 0;
    for (int g = 0; g < 5; g++) { gbaseT[g] = o; o += (long)128 * GPITCH[g]; }
  }
  int* POSg[5];
  {
    int o = 0;
    for (int g = 0; g < 5; g++) { POSg[g] = POSB + o; o += NT[GD[g]]; }
  }

  // 1) weight prep + POS permutation
  {
    WTStackArgs wa{};
    int j = 0;
    for (int g = 0; g < 5; g++) {
      wa.gnr[g] = GNR[g];
      for (int i = 0; i < 6; i++) wa.grel[g][i] = GRELS[g][i];
      for (int s = 0; s <= GNR[g]; s++, j++) {
        wa.srcrel[j] = (s < GNR[g]) ? GRELS[g][s] : -1;
        wa.grp[j] = g;
        wa.outoff[j] = gbaseT[g];
        wa.koff[j] = s * 128;
        wa.pitch[j] = GPITCH[g];
      }
    }
    hipLaunchKernelGGL(wtstack_kernel, dim3(64, 23), dim3(256), 0, stream,
                       conv_wl, conv_wr, conv_bl, WTG, BLS, wa);
  }
  {
    WTArgs pa{};
    int s = 0;
    auto add = [&](const float* W, u16* o, int K, int N, int Kpad) {
      pa.W[s] = W; pa.out[s] = o; pa.K[s] = K; pa.N[s] = N; pa.Kpad[s] = Kpad; s++;
    };
    add(W_in_atac,  WTIA, 257, 128, 288);
    add(W_in_gene,  WTIG, 129, 128, 160);
    add(W_in_pname, WTIP, 129, 128, 160);
    for (int g = 0; g < 5; g++) {
      int d = GD[g];
      add(mlp_w1 + (long)d * 128 * 256, WTM1 + (long)g * 32768, 128, 256, 128);
      add(mlp_w2 + (long)d * 256 * 128, WTM2 + (long)g * 32768, 256, 128, 256);
    }
    add(gd_w1, WTHD, 128, 256, 128);
    add(gv_w1, WTHV, 128, 256, 128);
    hipLaunchKernelGGL(wt_kernel, dim3(144, 15), dim3(256), 0, stream, pa);
  }
  {
    PosArgs pa{};
    for (int g = 0; g < 5; g++) {
      int d = GD[g];
      pa.m0[g] = mapin(d, 0); pa.m1[g] = mapin(d, 1); pa.pos[g] = POSg[g]; pa.n[g] = NT[d];
    }
    hipLaunchKernelGGL(pos_kernel, dim3(98, 5), dim3(256), 0, stream, pa);
  }

  // 2) all fp32->bf16 converts in ONE launch + batched input-linear GEMMs
  {
    PadArgs pc{};
    auto addp = [&](int s, const float* src, u16* dst, int M, int K, int Kpad) {
      pc.src[s] = src; pc.dst[s] = dst; pc.K[s] = K;
      pc.Kpad8[s] = Kpad / 8; pc.total[s] = M * (Kpad / 8);
      pc.aligned[s] = ((K & 7) == 0) ? 1 : 0;
    };
    addp(0, xin(0,0), PAD[0], 25000, 257, 288);
    addp(1, xin(1,0), PAD[1], 15000, 129, 160);
    addp(2, xin(4,0), PAD[2], 12000, 129, 160);
    addp(3, xin(0,1), PAD[3], 25000, 257, 288);
    addp(4, xin(1,1), PAD[4], 15000, 129, 160);
    addp(5, xin(2,0), XB0[2],  4000, 128, 128);
    addp(6, xin(3,0), XB0[3], 12000, 128, 128);
    addp(7, xin(5,0), XB0[5], 15000, 128, 128);
    addp(8, xin(2,1), XB1[2],  4000, 128, 128);
    addp(9, xin(3,1), XB1[3], 12000, 128, 128);
    addp(10, xin(5,1), XB1[5], 15000, 128, 128);
    hipLaunchKernelGGL(padcvt_kernel, dim3(3516, 11), dim3(256), 0, stream, pc);

    InLinBArgs ia{};
    auto add = [&](int s, const u16* A, const u16* WT, const float* b, u16* C,
                   int M, int Kpad) {
      ia.A[s] = A; ia.WT[s] = WT; ia.bias[s] = b; ia.C[s] = C;
      ia.M[s] = M; ia.Kpad[s] = Kpad;
    };
    add(0, PAD[0], WTIA, b_in_atac,  XB0[0], 25000, 288);
    add(1, PAD[1], WTIG, b_in_gene,  XB0[1], 15000, 160);
    add(2, PAD[2], WTIP, b_in_pname, XB0[4], 12000, 160);
    add(3, PAD[3], WTIA, b_in_atac,  XB1[0], 25000, 288);
    add(4, PAD[4], WTIG, b_in_gene,  XB1[1], 15000, 160);
    hipLaunchKernelGGL(tgemm_inb, dim3(391, 1, 5), dim3(256), 0, stream, ia);
  }

  // 3) CSR build (combined L0 18 + L1 6 slots)
  static const int L0R[18] = {0,1,2,3,4,5,6,7,8,9,10,12,13,14,15,16,17,18};
  static const int L1R[6]  = {2, 4, 7, 9, 15, 17};
  int rpoffByRel[19], slotByRel[19], rpoff1[19], slot1[19];
  CsrArgs cc{};
  {
    int ro = 0, bo = 0, s = 0;
    for (int i = 0; i < 18; i++, s++) {
      int r = L0R[i];
      cc.relid[s] = r; cc.lay[s] = 0; int nd = NT[REL_D[r]];
      cc.nd[s] = nd; cc.rpoff[s] = ro;
      cc.bkoff[s] = bo; cc.bboff[s] = bo + s; cc.nb[s] = (nd + 127) >> 7;
      rpoffByRel[r] = ro; slotByRel[r] = s;
      ro += nd + 1; bo += cc.nb[s];
    }
    for (int i = 0; i < 6; i++, s++) {
      int r = L1R[i];
      cc.relid[s] = r; cc.lay[s] = 1;
      cc.nd[s] = 15000; cc.rpoff[s] = ro;
      cc.bkoff[s] = bo; cc.bboff[s] = bo + s; cc.nb[s] = (15000 + 127) >> 7;
      rpoff1[r] = ro; slot1[r] = s;
      ro += 15001; bo += cc.nb[s];
    }
    hipMemsetAsync(BCNT, 0, (size_t)bo * 4, stream);
    hipLaunchKernelGGL(bhist_kernel, dim3(24 * 25), dim3(256), 0, stream, edges0, edges1, BCNT, cc);
    hipLaunchKernelGGL(bscan_kernel, dim3(24), dim3(256), 0, stream, BCNT, BBASE, BCUR, cc);
    hipLaunchKernelGGL(bucket_scatter, dim3(24 * 25), dim3(256), 0, stream,
                       edges0, edges1, BCUR, TMP, cc);
    hipLaunchKernelGGL(bucket_to_csr, dim3(196, 24), dim3(256), 0, stream, TMP, BBASE, RP, ESRC, cc);
  }

  // 4) agg (18 gathered slots) -> fused conv+MLP1+MLP2+scatter (z=5)
  {
    AggAllArgs aa{};
    int j = 0;
    for (int g = 0; g < 5; g++) {
      int d = GD[g];
      for (int i = 0; i < GNR[g]; i++, j++) {
        int r = GRELS[g][i];
        aa.xsrc[j]   = XB0[REL_S[r]];
        aa.rowptr[j] = RP + rpoffByRel[r];
        aa.esrc[j]   = ESRC + (long)slotByRel[r] * E_EDGES;
        aa.dst[j] = ABUFg[g]; aa.nd[j] = NT[d]; aa.pitch[j] = GPA[g];
        aa.koff[j] = i * 128;
      }
    }
    hipLaunchKernelGGL(agg_all, dim3(1563, 18), dim3(256), 0, stream, aa);
  }
  {
    FusedArgs fa{};
    for (int g = 0; g < 5; g++) {
      int d = GD[g];
      fa.A[g] = ABUFg[g]; fa.selfA[g] = XB0[d];
      fa.WTC[g] = WTG + gbaseT[g]; fa.biasC[g] = BLS + g * 128;
      fa.W1[g] = WTM1 + (long)g * 32768; fa.b1[g] = mlp_b1 + d * 256;
      fa.W2[g] = WTM2 + (long)g * 32768; fa.b2[g] = mlp_b2 + d * 128;
      fa.POS[g] = POSg[g]; fa.C[g] = XB1[d];
      fa.M[g] = NT[d]; fa.kself[g] = GPA[g]; fa.Kpad[g] = GPITCH[g];
    }
    hipLaunchKernelGGL(fused_mlp, dim3(391, 1, 5), dim3(256), 0, stream, fa);
  }

  // 5) layer-1 gene conv: agg (6 slots) + conv (direct self) -> G1B (bf16)
  {
    AggAllArgs aa{};
    for (int i = 0; i < 6; i++) {
      int r = L1R[i];
      aa.xsrc[i]   = XB1[REL_S[r]];
      aa.rowptr[i] = RP + rpoff1[r];
      aa.esrc[i]   = ESRC + (long)slot1[r] * E_EDGES;
      aa.dst[i] = ABUF; aa.nd[i] = 15000; aa.pitch[i] = 768;
      aa.koff[i] = i * 128;
    }
    hipLaunchKernelGGL(agg_all, dim3(938, 6), dim3(256), 0, stream, aa);
    hipLaunchKernelGGL(conv_l1, dim3(235), dim3(256), 0, stream,
                       ABUF, XB1[1], WTG + gbaseT[1], BLS + 1 * 128, G1B,
                       15000, 768, 896);
  }

  // 6) gene heads: batched MFMA (z=2, bf16 A) + batched reduce
  {
    HeadArgs ha{};
    ha.WT[0] = WTHD; ha.WT[1] = WTHV;
    ha.b1[0] = gd_b1; ha.b1[1] = gv_b1;
    ha.hid[0] = HIDF0; ha.hid[1] = HIDF1;
    ha.A = G1B; ha.M = 15000;
    hipLaunchKernelGGL(tgemm_head, dim3(235, 2, 2), dim3(256), 0, stream, ha);
    HeadRArgs hr{};
    hr.hid[0] = HIDF0; hr.hid[1] = HIDF1;
    hr.w2[0] = gd_w2; hr.w2[1] = gv_w2;
    hr.b2[0] = gd_b2; hr.b2[1] = gv_b2;
    hr.out = out; hr.M = 15000;
    hipLaunchKernelGGL(head_reduce2, dim3(3750, 2), dim3(256), 0, stream, hr);
  }
}

// Round 7
// 525.947 us; speedup vs baseline: 1.2642x; 1.2642x over previous
//
#include <hip/hip_runtime.h>
#include <math.h>

#define E_EDGES 100000

typedef unsigned short u16;
typedef unsigned int u32;

using bfrag = __attribute__((ext_vector_type(8))) short;
using ffrag = __attribute__((ext_vector_type(4))) float;

__device__ inline float bf2f(u32 u) { union { u32 i; float f; } c; c.i = u << 16; return c.f; }
__device__ inline u16 f2bf(float f) {
  union { u32 i; float f; } c; c.f = f;
  u32 u = c.i;
  return (u16)((u + 0x7FFFu + ((u >> 16) & 1u)) >> 16);
}

// ---------------- structs ----------------
struct CsrArgs { int relid[24]; int lay[24]; int nd[24]; int rpoff[24];
                 int bkoff[24]; int bboff[24]; int nb[24]; };

struct AggAllArgs {
  const u16* xsrc[18];
  const int* rowptr[18];
  const int* esrc[18];
  u16* dst[18];
  int nd[18]; int pitch[18]; int koff[18];
};

struct WTStackArgs {
  int srcrel[23]; int grp[23]; long outoff[23]; int koff[23]; int pitch[23];
  int gnr[5]; int grel[5][6];
};

struct WTArgs { const float* W[15]; u16* out[15]; int K[15]; int N[15]; int Kpad[15]; };
struct PadArgs { const float* src[11]; u16* dst[11]; int K[11]; int Kpad8[11];
                 int total[11]; int aligned[11]; };
struct InLinBArgs { const u16* A[5]; const u16* WT[5]; const float* bias[5]; u16* C[5];
                    int M[5]; int Kpad[5]; };
struct FusedArgs {
  const u16* A[5]; const u16* selfA[5]; const u16* WTC[5]; const float* biasC[5];
  const u16* W1[5]; const float* b1[5]; const u16* W2[5]; const float* b2[5];
  const int* POS[5]; u16* C[5]; int M[5]; int kself[5]; int Kpad[5];
};
struct PosArgs { const int* m0[5]; const int* m1[5]; int* pos[5]; int n[5]; };
struct HeadArgs { const u16* WT[2]; const float* b1[2]; float* hid[2]; const u16* A; int M; };
struct HeadRArgs { const float* hid[2]; const float* w2[2]; const float* b2[2]; float* out; int M; };

// ---------------- batched bf16 GEMM (input linears), N=128 ------------
__global__ __launch_bounds__(256) void tgemm_inb(InLinBArgs a)
{
  const int z = blockIdx.z;
  const int M = a.M[z], Kpad = a.Kpad[z];
  const int rowbase = blockIdx.x * 64;
  if (rowbase >= M) return;
  __shared__ u16 sA[64 * 40];
  __shared__ u16 sB[128 * 40];
  const int tid = threadIdx.x;
  const int w = tid >> 6, lane = tid & 63;
  const int quad = lane >> 4, m = lane & 15;
  const int sr = tid >> 2, sc = tid & 3;
  const int br = tid >> 1, bh = tid & 1;
  const u16* A = a.A[z];
  const u16* WT = a.WT[z];
  ffrag acc[8];
  #pragma unroll
  for (int i = 0; i < 8; i++) { acc[i][0] = 0.f; acc[i][1] = 0.f; acc[i][2] = 0.f; acc[i][3] = 0.f; }

  for (int kt = 0; kt < Kpad / 32; kt++) {
    int gr = rowbase + sr, gk = kt * 32 + sc * 8;
    uint4 st = make_uint4(0, 0, 0, 0);
    if (gr < M) st = *(const uint4*)(A + (long)gr * Kpad + gk);
    const u16* wrow = WT + (long)br * Kpad + kt * 32 + bh * 16;
    uint4 b0 = *(const uint4*)wrow;
    uint4 b1 = *(const uint4*)(wrow + 8);

    if (kt) __syncthreads();
    *(uint4*)&sA[sr * 40 + sc * 8] = st;
    *(uint4*)&sB[br * 40 + bh * 16] = b0;
    *(uint4*)&sB[br * 40 + bh * 16 + 8] = b1;
    __syncthreads();

    bfrag av = *(const bfrag*)&sA[(w * 16 + m) * 40 + quad * 8];
    #pragma unroll
    for (int ct = 0; ct < 8; ct++) {
      bfrag bv = *(const bfrag*)&sB[(ct * 16 + m) * 40 + quad * 8];
      acc[ct] = __builtin_amdgcn_mfma_f32_16x16x32_bf16(av, bv, acc[ct], 0, 0, 0);
    }
  }

  const float* bias = a.bias[z];
  u16* C = a.C[z];
  #pragma unroll
  for (int ct = 0; ct < 8; ct++) {
    int col = ct * 16 + m;
    float bv = bias[col];
    #pragma unroll
    for (int r = 0; r < 4; r++) {
      int row = rowbase + w * 16 + quad * 4 + r;
      if (row < M) C[(long)row * 128 + col] = f2bf(acc[ct][r] + bv);
    }
  }
}

// ------- fused conv + MLP1(relu) + MLP2 + POS-scatter (per dst group, z-batched) -----
// LDS-staged GEMM bodies (round-5 structure). Inter-stage buffers use stride 140 u16
// (70 words = 6 mod 32) -> <=2 lanes/bank on ds_read_b128 and distinct banks on u16
// writes (2-way is free per LDS bank rules); stride 136 was 8-way/4-way conflicted.
// LDS overlay (u16): sB[0,5120) sA[5120,7680) m1[7680,16640)
//                    m2b[5120,14080) (after m1 dead)  m2a[16640,25600)
#define MSTR 140
__global__ __launch_bounds__(256) void fused_mlp(FusedArgs a)
{
  const int z = blockIdx.z;
  const int M = a.M[z];
  const int rowbase = blockIdx.x * 64;
  if (rowbase >= M) return;
  __shared__ u16 LDS[25600];
  u16* sB  = LDS;
  u16* sA  = LDS + 5120;
  u16* m1  = LDS + 7680;   // 64 x 140
  u16* m2b = LDS + 5120;   // 64 x 140 (overlays sA + head of m1)
  u16* m2a = LDS + 16640;  // 64 x 140
  const int tid = threadIdx.x;
  const int w = tid >> 6, lane = tid & 63;
  const int quad = lane >> 4, m = lane & 15;
  const int sr = tid >> 2, sc = tid & 3;
  const int br = tid >> 1, bh = tid & 1;
  const int kself = a.kself[z], Kpad = a.Kpad[z];
  const u16* A = a.A[z];
  const u16* selfA = a.selfA[z];

  // ---- stage 1: conv GEMM (gathered K-blocks from A, self block from selfA) ----
  {
    const u16* WT = a.WTC[z];
    ffrag acc[8];
    #pragma unroll
    for (int i = 0; i < 8; i++) { acc[i][0] = 0.f; acc[i][1] = 0.f; acc[i][2] = 0.f; acc[i][3] = 0.f; }
    for (int kt = 0; kt < Kpad / 32; kt++) {
      int gr = rowbase + sr, gk = kt * 32 + sc * 8;
      uint4 st = make_uint4(0, 0, 0, 0);
      if (gr < M) {
        const u16* src = (gk < kself) ? (A + (long)gr * kself + gk)
                                      : (selfA + (long)gr * 128 + (gk - kself));
        st = *(const uint4*)src;
      }
      const u16* wrow = WT + (long)br * Kpad + kt * 32 + bh * 16;
      uint4 b0 = *(const uint4*)wrow;
      uint4 b1 = *(const uint4*)(wrow + 8);

      if (kt) __syncthreads();
      *(uint4*)&sA[sr * 40 + sc * 8] = st;
      *(uint4*)&sB[br * 40 + bh * 16] = b0;
      *(uint4*)&sB[br * 40 + bh * 16 + 8] = b1;
      __syncthreads();

      bfrag av = *(const bfrag*)&sA[(w * 16 + m) * 40 + quad * 8];
      #pragma unroll
      for (int ct = 0; ct < 8; ct++) {
        bfrag bv = *(const bfrag*)&sB[(ct * 16 + m) * 40 + quad * 8];
        acc[ct] = __builtin_amdgcn_mfma_f32_16x16x32_bf16(av, bv, acc[ct], 0, 0, 0);
      }
    }
    // conv epilogue -> m1 (bf16 + bias); m1 is disjoint from sA/sB, no barrier needed yet
    const float* bc = a.biasC[z];
    #pragma unroll
    for (int ct = 0; ct < 8; ct++) {
      int col = ct * 16 + m;
      float bv = bc[col];
      #pragma unroll
      for (int r = 0; r < 4; r++) {
        int row = w * 16 + quad * 4 + r;
        m1[row * MSTR + col] = f2bf(acc[ct][r] + bv);
      }
    }
  }

  // ---- stage 2: MLP1 (K=128 from m1, N=256 in two col-halves, relu) ----
  {
    const u16* W1 = a.W1[z];
    const float* b1p = a.b1[z];
    for (int h = 0; h < 2; h++) {
      ffrag acch[8];
      #pragma unroll
      for (int i = 0; i < 8; i++) { acch[i][0] = 0.f; acch[i][1] = 0.f; acch[i][2] = 0.f; acch[i][3] = 0.f; }
      for (int kt = 0; kt < 4; kt++) {
        const u16* wrow = W1 + (long)(h * 128 + br) * 128 + kt * 32 + bh * 16;
        uint4 b0 = *(const uint4*)wrow;
        uint4 b1v = *(const uint4*)(wrow + 8);
        __syncthreads();                    // prior sB readers done; m1 visible (1st iter)
        *(uint4*)&sB[br * 40 + bh * 16] = b0;
        *(uint4*)&sB[br * 40 + bh * 16 + 8] = b1v;
        __syncthreads();
        bfrag av = *(const bfrag*)&m1[(w * 16 + m) * MSTR + kt * 32 + quad * 8];
        #pragma unroll
        for (int ct = 0; ct < 8; ct++) {
          bfrag bv = *(const bfrag*)&sB[(ct * 16 + m) * 40 + quad * 8];
          acch[ct] = __builtin_amdgcn_mfma_f32_16x16x32_bf16(av, bv, acch[ct], 0, 0, 0);
        }
      }
      u16* dstm = h ? m2b : m2a;
      if (h) __syncthreads();               // m2b overlays m1: all m1 readers must be done
      #pragma unroll
      for (int ct = 0; ct < 8; ct++) {
        int col = ct * 16 + m;
        float bv = b1p[h * 128 + col];
        #pragma unroll
        for (int r = 0; r < 4; r++) {
          int row = w * 16 + quad * 4 + r;
          dstm[row * MSTR + col] = f2bf(fmaxf(acch[ct][r] + bv, 0.f));
        }
      }
    }
  }

  // ---- stage 3: MLP2 (K=256 from m2a/m2b, N=128) + POS scatter ----
  {
    const u16* W2 = a.W2[z];
    ffrag acc2[8];
    #pragma unroll
    for (int i = 0; i < 8; i++) { acc2[i][0] = 0.f; acc2[i][1] = 0.f; acc2[i][2] = 0.f; acc2[i][3] = 0.f; }
    for (int kt = 0; kt < 8; kt++) {
      const u16* wrow = W2 + (long)br * 256 + kt * 32 + bh * 16;
      uint4 b0 = *(const uint4*)wrow;
      uint4 b1v = *(const uint4*)(wrow + 8);
      __syncthreads();                      // prior sB readers done; m2b visible (1st iter)
      *(uint4*)&sB[br * 40 + bh * 16] = b0;
      *(uint4*)&sB[br * 40 + bh * 16 + 8] = b1v;
      __syncthreads();
      const u16* msrc = (kt < 4) ? m2a : m2b;
      bfrag av = *(const bfrag*)&msrc[(w * 16 + m) * MSTR + (kt & 3) * 32 + quad * 8];
      #pragma unroll
      for (int ct = 0; ct < 8; ct++) {
        bfrag bv = *(const bfrag*)&sB[(ct * 16 + m) * 40 + quad * 8];
        acc2[ct] = __builtin_amdgcn_mfma_f32_16x16x32_bf16(av, bv, acc2[ct], 0, 0, 0);
      }
    }
    const int* POS = a.POS[z];
    const float* b2p = a.b2[z];
    u16* C = a.C[z];
    #pragma unroll
    for (int ct = 0; ct < 8; ct++) {
      int col = ct * 16 + m;
      float bv = b2p[col];
      #pragma unroll
      for (int r = 0; r < 4; r++) {
        int row = rowbase + w * 16 + quad * 4 + r;
        if (row < M) {
          int j = POS[row];
          if (j >= 0) C[(long)j * 128 + col] = f2bf(acc2[ct][r] + bv);
        }
      }
    }
  }
}

// ---------------- L1 gene conv: gathered A + direct self, bf16 out ----------------
__global__ __launch_bounds__(256) void conv_l1(const u16* __restrict__ A,
                                               const u16* __restrict__ selfA,
                                               const u16* __restrict__ WT,
                                               const float* __restrict__ bias,
                                               u16* __restrict__ C,
                                               int M, int kself, int Kpad)
{
  const int rowbase = blockIdx.x * 64;
  if (rowbase >= M) return;
  __shared__ u16 sA[64 * 40];
  __shared__ u16 sB[128 * 40];
  const int tid = threadIdx.x;
  const int w = tid >> 6, lane = tid & 63;
  const int quad = lane >> 4, m = lane & 15;
  const int sr = tid >> 2, sc = tid & 3;
  const int br = tid >> 1, bh = tid & 1;
  ffrag acc[8];
  #pragma unroll
  for (int i = 0; i < 8; i++) { acc[i][0] = 0.f; acc[i][1] = 0.f; acc[i][2] = 0.f; acc[i][3] = 0.f; }

  for (int kt = 0; kt < Kpad / 32; kt++) {
    int gr = rowbase + sr, gk = kt * 32 + sc * 8;
    uint4 st = make_uint4(0, 0, 0, 0);
    if (gr < M) {
      const u16* src = (gk < kself) ? (A + (long)gr * kself + gk)
                                    : (selfA + (long)gr * 128 + (gk - kself));
      st = *(const uint4*)src;
    }
    const u16* wrow = WT + (long)br * Kpad + kt * 32 + bh * 16;
    uint4 b0 = *(const uint4*)wrow;
    uint4 b1 = *(const uint4*)(wrow + 8);

    if (kt) __syncthreads();
    *(uint4*)&sA[sr * 40 + sc * 8] = st;
    *(uint4*)&sB[br * 40 + bh * 16] = b0;
    *(uint4*)&sB[br * 40 + bh * 16 + 8] = b1;
    __syncthreads();

    bfrag av = *(const bfrag*)&sA[(w * 16 + m) * 40 + quad * 8];
    #pragma unroll
    for (int ct = 0; ct < 8; ct++) {
      bfrag bv = *(const bfrag*)&sB[(ct * 16 + m) * 40 + quad * 8];
      acc[ct] = __builtin_amdgcn_mfma_f32_16x16x32_bf16(av, bv, acc[ct], 0, 0, 0);
    }
  }

  #pragma unroll
  for (int ct = 0; ct < 8; ct++) {
    int col = ct * 16 + m;
    float bv = bias[col];
    #pragma unroll
    for (int r = 0; r < 4; r++) {
      int row = rowbase + w * 16 + quad * 4 + r;
      if (row < M) C[(long)row * 128 + col] = f2bf(acc[ct][r] + bv);
    }
  }
}

// ---------------- streaming fp32 -> padded bf16 convert (11 slots, one launch) -------
__global__ __launch_bounds__(256) void padcvt_kernel(PadArgs a)
{
  const int z = blockIdx.y;
  int idx = blockIdx.x * 256 + threadIdx.x;
  if (idx >= a.total[z]) return;
  const int kp8 = a.Kpad8[z];
  const int K = a.K[z];
  int row = idx / kp8;
  int c8 = idx - row * kp8;
  int base = c8 * 8;
  u32 wv[4];
  if (a.aligned[z]) {
    const float4* src = (const float4*)(a.src[z] + (long)row * K + base);
    float4 f0 = src[0];
    float4 f1 = src[1];
    wv[0] = (u32)f2bf(f0.x) | ((u32)f2bf(f0.y) << 16);
    wv[1] = (u32)f2bf(f0.z) | ((u32)f2bf(f0.w) << 16);
    wv[2] = (u32)f2bf(f1.x) | ((u32)f2bf(f1.y) << 16);
    wv[3] = (u32)f2bf(f1.z) | ((u32)f2bf(f1.w) << 16);
  } else {
    const float* src = a.src[z] + (long)row * K + base;
    #pragma unroll
    for (int i = 0; i < 4; i++) {
      float lo = (base + 2 * i     < K) ? src[2 * i]     : 0.f;
      float hi = (base + 2 * i + 1 < K) ? src[2 * i + 1] : 0.f;
      wv[i] = (u32)f2bf(lo) | ((u32)f2bf(hi) << 16);
    }
  }
  *(uint4*)(a.dst[z] + (long)row * (kp8 * 8) + base) = make_uint4(wv[0], wv[1], wv[2], wv[3]);
}

// ---------------- batched gene heads (bf16 A, fp32 out, relu, N=256) ----------------
__global__ __launch_bounds__(256) void tgemm_head(HeadArgs a)
{
  const int z = blockIdx.z;
  const int M = a.M;
  const int rowbase = blockIdx.x * 64;
  const int colbase = blockIdx.y * 128;
  __shared__ u16 sA[64 * 40];
  __shared__ u16 sB[128 * 40];
  const int tid = threadIdx.x;
  const int w = tid >> 6, lane = tid & 63;
  const int quad = lane >> 4, m = lane & 15;
  const int sr = tid >> 2, sc = tid & 3;
  const int br = tid >> 1, bh = tid & 1;
  const u16* A = a.A;
  const u16* WT = a.WT[z];
  ffrag acc[8];
  #pragma unroll
  for (int i = 0; i < 8; i++) { acc[i][0] = 0.f; acc[i][1] = 0.f; acc[i][2] = 0.f; acc[i][3] = 0.f; }

  for (int kt = 0; kt < 4; kt++) {
    int gr = rowbase + sr, gk = kt * 32 + sc * 8;
    uint4 st = make_uint4(0, 0, 0, 0);
    if (gr < M) st = *(const uint4*)(A + (long)gr * 128 + gk);
    const u16* wrow = WT + (long)(colbase + br) * 128 + kt * 32 + bh * 16;
    uint4 b0 = *(const uint4*)wrow;
    uint4 b1 = *(const uint4*)(wrow + 8);

    if (kt) __syncthreads();
    *(uint4*)&sA[sr * 40 + sc * 8] = st;
    *(uint4*)&sB[br * 40 + bh * 16] = b0;
    *(uint4*)&sB[br * 40 + bh * 16 + 8] = b1;
    __syncthreads();

    bfrag av = *(const bfrag*)&sA[(w * 16 + m) * 40 + quad * 8];
    #pragma unroll
    for (int ct = 0; ct < 8; ct++) {
      bfrag bv = *(const bfrag*)&sB[(ct * 16 + m) * 40 + quad * 8];
      acc[ct] = __builtin_amdgcn_mfma_f32_16x16x32_bf16(av, bv, acc[ct], 0, 0, 0);
    }
  }

  const float* bias = a.b1[z];
  float* C = a.hid[z];
  #pragma unroll
  for (int ct = 0; ct < 8; ct++) {
    int col = colbase + ct * 16 + m;
    float bv = bias[col];
    #pragma unroll
    for (int r = 0; r < 4; r++) {
      int row = rowbase + w * 16 + quad * 4 + r;
      if (row < M) C[(long)row * 256 + col] = fmaxf(acc[ct][r] + bv, 0.f);
    }
  }
}

// ---------------- CSR build: bucket-level histogram (LDS-privatized) ----------------
__global__ __launch_bounds__(256) void bhist_kernel(const int* __restrict__ e0,
                                                    const int* __restrict__ e1,
                                                    int* __restrict__ bcnt, CsrArgs a)
{
  const int slot = blockIdx.x / 25;
  const int ch = blockIdx.x % 25;
  const int base = ch * 4096;
  const int n = (E_EDGES - base < 4096) ? (E_EDGES - base) : 4096;
  const int* E = a.lay[slot] ? e1 : e0;
  const int r = a.relid[slot];
  const int tid = threadIdx.x;
  __shared__ int h[256];
  h[tid] = 0;
  __syncthreads();
  const int* darr = E + (r * 2 + 1) * E_EDGES + base;
  for (int i = tid; i < n; i += 256) atomicAdd(&h[darr[i] >> 7], 1);
  __syncthreads();
  if (tid < a.nb[slot] && h[tid]) atomicAdd(&bcnt[a.bkoff[slot] + tid], h[tid]);
}

// per-slot scan of bucket counts -> bucket bases (exclusive, + sentinel) and cursors
__global__ __launch_bounds__(256) void bscan_kernel(const int* __restrict__ bcnt,
                                                    int* __restrict__ bbase,
                                                    int* __restrict__ bcur, CsrArgs a)
{
  int slot = blockIdx.x;
  int nb = a.nb[slot];
  int tid = threadIdx.x, lane = tid & 63, w = tid >> 6;
  __shared__ int ws[4];
  int v = (tid < nb) ? bcnt[a.bkoff[slot] + tid] : 0;
  int si = v;
  #pragma unroll
  for (int off = 1; off < 64; off <<= 1) {
    int t = __shfl_up(si, off, 64);
    if (lane >= off) si += t;
  }
  if (lane == 63) ws[w] = si;
  __syncthreads();
  int woff = 0;
  #pragma unroll
  for (int k = 0; k < 4; k++) if (k < w) woff += ws[k];
  int excl = woff + si - v;
  if (tid < nb) { bbase[a.bboff[slot] + tid] = excl; bcur[a.bkoff[slot] + tid] = excl; }
  if (tid == 0) bbase[a.bboff[slot] + nb] = ws[0] + ws[1] + ws[2] + ws[3];
}

// pass B: per-block LDS bucketing + coalesced burst append into TMP
__global__ __launch_bounds__(256) void bucket_scatter(const int* __restrict__ e0,
                                                      const int* __restrict__ e1,
                                                      int* __restrict__ bcur,
                                                      u32* __restrict__ tmp, CsrArgs a)
{
  const int slot = blockIdx.x / 25;
  const int ch = blockIdx.x % 25;
  const int base = ch * 4096;
  const int n = (E_EDGES - base < 4096) ? (E_EDGES - base) : 4096;
  const int* E = a.lay[slot] ? e1 : e0;
  const int r = a.relid[slot];
  const int nb = a.nb[slot];
  const int tid = threadIdx.x;
  __shared__ int hist[256], start[256], gbase[256], lcur[256];
  __shared__ u32 sorted[4096];
  hist[tid] = 0;
  __syncthreads();
  const int* darr = E + (r * 2 + 1) * E_EDGES + base;
  const int* sarr = E + r * 2 * E_EDGES + base;
  for (int i = tid; i < n; i += 256) atomicAdd(&hist[darr[i] >> 7], 1);
  __syncthreads();
  if (tid == 0) {
    int s = 0;
    for (int b = 0; b < nb; b++) { start[b] = s; s += hist[b]; }
  }
  __syncthreads();
  if (tid < nb) {
    gbase[tid] = atomicAdd(&bcur[a.bkoff[slot] + tid], hist[tid]);
    lcur[tid] = start[tid];
  }
  __syncthreads();
  for (int i = tid; i < n; i += 256) {
    int dst = darr[i], src = sarr[i];
    int pos = atomicAdd(&lcur[dst >> 7], 1);
    sorted[pos] = ((u32)dst << 16) | (u32)src;
  }
  __syncthreads();
  u32* out = tmp + (long)slot * E_EDGES;
  for (int i = tid; i < n; i += 256) {
    u32 p = sorted[i];
    int b = p >> 23;
    out[gbase[b] + (i - start[b])] = p;
  }
}

// pass C: per-(slot,bucket): derive rowptr segment + LDS counting-sort into CSR
__global__ __launch_bounds__(256) void bucket_to_csr(const u32* __restrict__ tmp,
                                                     const int* __restrict__ bbase,
                                                     int* __restrict__ rp,
                                                     int* __restrict__ esrc, CsrArgs a)
{
  const int b = blockIdx.x, slot = blockIdx.y;
  if (b >= a.nb[slot]) return;
  const int rb = a.rpoff[slot];
  const int bb = bbase[a.bboff[slot] + b];
  const int be = bbase[a.bboff[slot] + b + 1];
  const int cnt = be - bb;
  const int rowlo = b << 7;
  int rowhi = rowlo + 128; if (rowhi > a.nd[slot]) rowhi = a.nd[slot];
  const int nrow = rowhi - rowlo;
  const int tid = threadIdx.x;
  __shared__ int rcnt[128];
  __shared__ int rpref[129];
  __shared__ int scur[128];
  __shared__ u32 sbuf[8192];
  if (tid < 128) rcnt[tid] = 0;
  __syncthreads();
  const u32* in = tmp + (long)slot * E_EDGES + bb;
  for (int i = tid; i < cnt; i += 256) atomicAdd(&rcnt[(in[i] >> 16) & 127], 1);
  __syncthreads();
  if (tid == 0) {
    int s = 0;
    for (int t = 0; t < 128; t++) { rpref[t] = s; s += rcnt[t]; }
    rpref[128] = s;
  }
  __syncthreads();
  if (tid < nrow) rp[rb + rowlo + tid] = bb + rpref[tid];
  if (tid == 0) rp[rb + rowhi] = be;
  if (tid < 128) scur[tid] = rpref[tid];
  __syncthreads();
  int* out = esrc + (long)slot * E_EDGES + bb;
  if (cnt <= 8192) {
    for (int i = tid; i < cnt; i += 256) {
      u32 p = in[i];
      int pos = atomicAdd(&scur[(p >> 16) & 127], 1);
      sbuf[pos] = p & 0xFFFFu;
    }
    __syncthreads();
    for (int i = tid; i < cnt; i += 256) out[i] = (int)sbuf[i];
  } else {
    for (int i = tid; i < cnt; i += 256) {
      u32 p = in[i];
      int pos = atomicAdd(&scur[(p >> 16) & 127], 1);
      out[pos] = (int)(p & 0xFFFFu);
    }
  }
}

// ---------------- weight prep ----------------
__global__ __launch_bounds__(256) void wtstack_kernel(const float* __restrict__ wl,
                                                      const float* __restrict__ wr,
                                                      const float* __restrict__ bl,
                                                      u16* __restrict__ WTG,
                                                      float* __restrict__ BLS, WTStackArgs a)
{
  int slot = blockIdx.y;
  int t = blockIdx.x * 256 + threadIdx.x;
  int krel = t & 127, n = t >> 7;
  int sr = a.srcrel[slot];
  float v;
  if (sr >= 0) {
    v = wl[(long)sr * 16384 + krel * 128 + n];
  } else {
    int g = a.grp[slot];
    v = 0.f;
    for (int i = 0; i < a.gnr[g]; i++) v += wr[(long)a.grel[g][i] * 16384 + krel * 128 + n];
    if (t < 128) {
      float b = 0.f;
      for (int i = 0; i < a.gnr[g]; i++) b += bl[a.grel[g][i] * 128 + t];
      BLS[g * 128 + t] = b;
    }
  }
  WTG[a.outoff[slot] + (long)n * a.pitch[slot] + a.koff[slot] + krel] = f2bf(v);
}

__global__ __launch_bounds__(256) void wt_kernel(WTArgs a)
{
  int s = blockIdx.y;
  int idx = blockIdx.x * 256 + threadIdx.x;
  int K = a.K[s], N = a.N[s], Kpad = a.Kpad[s];
  if (idx >= N * Kpad) return;
  int n = idx / Kpad, k = idx - n * Kpad;
  a.out[s][idx] = (k < K) ? f2bf(a.W[s][(long)k * N + n]) : (u16)0;
}

__global__ __launch_bounds__(256) void pos_kernel(PosArgs a)
{
  int g = blockIdx.y;
  int i = blockIdx.x * 256 + threadIdx.x;
  if (i >= a.n[g]) return;
  int key = a.m0[g][i];
  const int* m1 = a.m1[g];
  int lo = 0, hi = a.n[g] - 1, pos = -1;
  while (lo <= hi) {
    int mid = (lo + hi) >> 1;
    int v = m1[mid];
    if (v == key) { pos = mid; break; }
    if (v < key) lo = mid + 1; else hi = mid - 1;
  }
  a.pos[g][i] = pos;
}

// ---------------- aggregation: 16 lanes/row, dwordx4 gathers, 4-deep unroll ---------
__global__ __launch_bounds__(256) void agg_all(AggAllArgs a)
{
  int slot = blockIdx.y;
  int grp = threadIdx.x >> 4;
  int lane = threadIdx.x & 15;
  int row = blockIdx.x * 16 + grp;
  if (row >= a.nd[slot]) return;
  u16* dst = a.dst[slot] + (long)row * a.pitch[slot] + a.koff[slot] + lane * 8;
  const uint4* x4 = (const uint4*)a.xsrc[slot];
  const int* rp = a.rowptr[slot];
  int c0 = rp[row], c1 = rp[row + 1];
  const int* es = a.esrc[slot];
  float acc[8];
  #pragma unroll
  for (int i = 0; i < 8; i++) acc[i] = 0.f;
  int e = c0;
  for (; e + 4 <= c1; e += 4) {
    int s0 = es[e], s1 = es[e + 1], s2 = es[e + 2], s3 = es[e + 3];
    uint4 v0 = x4[(long)s0 * 16 + lane];
    uint4 v1 = x4[(long)s1 * 16 + lane];
    uint4 v2 = x4[(long)s2 * 16 + lane];
    uint4 v3 = x4[(long)s3 * 16 + lane];
    const u32* w0 = (const u32*)&v0;
    const u32* w1 = (const u32*)&v1;
    const u32* w2 = (const u32*)&v2;
    const u32* w3 = (const u32*)&v3;
    #pragma unroll
    for (int i = 0; i < 4; i++) {
      acc[2*i]   += bf2f(w0[i] & 0xFFFF) + bf2f(w1[i] & 0xFFFF)
                  + bf2f(w2[i] & 0xFFFF) + bf2f(w3[i] & 0xFFFF);
      acc[2*i+1] += bf2f(w0[i] >> 16) + bf2f(w1[i] >> 16)
                  + bf2f(w2[i] >> 16) + bf2f(w3[i] >> 16);
    }
  }
  for (; e < c1; e++) {
    uint4 v = x4[(long)es[e] * 16 + lane];
    const u32* wv = (const u32*)&v;
    #pragma unroll
    for (int i = 0; i < 4; i++) {
      acc[2*i]   += bf2f(wv[i] & 0xFFFF);
      acc[2*i+1] += bf2f(wv[i] >> 16);
    }
  }
  int c = c1 - c0;
  float inv = 1.f / (float)(c > 1 ? c : 1);
  u32 o[4];
  #pragma unroll
  for (int i = 0; i < 4; i++)
    o[i] = (u32)f2bf(acc[2*i] * inv) | ((u32)f2bf(acc[2*i+1] * inv) << 16);
  *(uint4*)dst = make_uint4(o[0], o[1], o[2], o[3]);
}

// ---------------- batched head reduce (4 rows/block) ----------------
__global__ __launch_bounds__(256) void head_reduce2(HeadRArgs a)
{
  int wave = threadIdx.x >> 6, lane = threadIdx.x & 63;
  int row = blockIdx.x * 4 + wave;
  int z = blockIdx.y;
  if (row >= a.M) return;
  const float* h = a.hid[z] + (long)row * 256;
  const float* w2 = a.w2[z];
  float s = h[lane] * w2[lane] + h[lane + 64] * w2[lane + 64]
          + h[lane + 128] * w2[lane + 128] + h[lane + 192] * w2[lane + 192];
  #pragma unroll
  for (int off = 32; off >= 1; off >>= 1) s += __shfl_down(s, off, 64);
  if (lane == 0) {
    float v = s + a.b2[z][0];
    if (z == 0) v = 1.0f / (1.0f + expf(-v));
    a.out[row * 2 + z] = v;
  }
}

// ---------------- host orchestration ----------------
extern "C" void kernel_launch(void* const* d_in, const int* in_sizes, int n_in,
                              void* d_out, int out_size, void* d_ws, size_t ws_size,
                              hipStream_t stream)
{
  static const int NT[6] = {25000, 15000, 4000, 12000, 12000, 15000};
  static const int REL_S[19] = {2,0,2,1,0,1,3,3,1,3,1,3,4,5,0,5,1,0,1};
  static const int REL_D[19] = {0,2,1,2,1,0,3,1,3,1,3,4,3,0,5,1,5,1,0};

  auto xin   = [&](int t, int L) { return (const float*)d_in[L * 13 + 2 * t]; };
  auto mapin = [&](int t, int L) { return (const int*)d_in[L * 13 + 2 * t + 1]; };
  const int* edges0 = (const int*)d_in[12];
  const int* edges1 = (const int*)d_in[25];
  const float* W_in_atac  = (const float*)d_in[26];
  const float* b_in_atac  = (const float*)d_in[27];
  const float* W_in_gene  = (const float*)d_in[28];
  const float* b_in_gene  = (const float*)d_in[29];
  const float* W_in_pname = (const float*)d_in[30];
  const float* b_in_pname = (const float*)d_in[31];
  const float* conv_wl = (const float*)d_in[32];
  const float* conv_bl = (const float*)d_in[33];
  const float* conv_wr = (const float*)d_in[34];
  const float* mlp_w1 = (const float*)d_in[35];
  const float* mlp_b1 = (const float*)d_in[36];
  const float* mlp_w2 = (const float*)d_in[37];
  const float* mlp_b2 = (const float*)d_in[38];
  const float* gd_w1 = (const float*)d_in[39];
  const float* gd_b1 = (const float*)d_in[40];
  const float* gd_w2 = (const float*)d_in[41];
  const float* gd_b2 = (const float*)d_in[42];
  const float* gv_w1 = (const float*)d_in[43];
  const float* gv_b1 = (const float*)d_in[44];
  const float* gv_w2 = (const float*)d_in[45];
  const float* gv_b2 = (const float*)d_in[46];
  float* out = (float*)d_out;

  // dst-type groups
  static const int GD[5]       = {0, 1, 2, 3, 5};
  static const int GNR[5]      = {4, 6, 2, 4, 2};
  static const int GRELS[5][6] = {{0,5,13,18,0,0},{2,4,7,9,15,17},{1,3,0,0,0,0},
                                  {6,8,10,12,0,0},{14,16,0,0,0,0}};
  static const int GPITCH[5]   = {640, 896, 384, 640, 384};  // WTG K (incl. self 128)
  static const int GPA[5]      = {512, 768, 256, 512, 256};  // gathered-only pitch

  // ---- workspace carve ----
  float* fp = (float*)d_ws;
  auto takef = [&](size_t n) { float* q = fp; fp += n; return q; };
  float* BLS  = takef(5 * 128);
  u16* bp = (u16*)fp;
  auto takeb = [&](size_t n) { u16* q = bp; bp += n; return q; };
  u16* XB0[6]; u16* XB1[6];
  XB0[0] = takeb((size_t)25000 * 128);
  XB0[1] = takeb((size_t)15000 * 128);
  XB0[2] = takeb((size_t)4000 * 128);
  XB0[3] = takeb((size_t)12000 * 128);
  XB0[4] = takeb((size_t)12000 * 128);
  XB0[5] = takeb((size_t)15000 * 128);
  XB1[0] = takeb((size_t)25000 * 128);
  XB1[1] = takeb((size_t)15000 * 128);
  XB1[2] = takeb((size_t)4000 * 128);
  XB1[3] = takeb((size_t)12000 * 128);
  XB1[4] = nullptr;
  XB1[5] = takeb((size_t)15000 * 128);
  u16* ABUF = takeb((size_t)35328000);       // per-group gathered agg (no self)
  u16* ABUFg[5];
  {
    long o = 0;
    for (int g = 0; g < 5; g++) { ABUFg[g] = ABUF + o; o += (long)NT[GD[g]] * GPA[g]; }
  }
  u16* G1B  = takeb((size_t)15000 * 128);    // L1 conv out (bf16)
  u16* WTG  = takeb(376832);
  u16* WTIA = takeb(128 * 288);
  u16* WTIG = takeb(128 * 160);
  u16* WTIP = takeb(128 * 160);
  u16* WTM1 = takeb((size_t)5 * 32768);
  u16* WTM2 = takeb((size_t)5 * 32768);
  u16* WTHD = takeb(32768);
  u16* WTHV = takeb(32768);
  uintptr_t ipa = ((uintptr_t)bp + 15) & ~(uintptr_t)15;
  int* ip = (int*)ipa;
  auto takei = [&](size_t n) { int* q = ip; ip += n; return q; };
  int* RP    = takei(366024);
  int* BCNT  = takei(4704);
  int* BBASE = takei(4728);
  int* BCUR  = takei(4704);
  int* POSB  = takei(71000);
  int* ESRC  = takei((size_t)24 * E_EDGES);
  // aliases inside ABUF (disjoint lifetimes, in-order stream):
  u32* TMP = (u32*)ABUF;                         // CSR staging (phase 3)
  float* HIDF0 = (float*)ABUF;                   // head hidden (phase 6)
  float* HIDF1 = (float*)(ABUF + (size_t)15000 * 256 * 2);
  u16* PAD[5];                                   // padded bf16 input-linear A (phase 2)
  PAD[0] = ABUF;                       // atac0  25000*288 = 7.20M
  PAD[1] = ABUF +  7200000;            // gene0  15000*160 = 2.40M
  PAD[2] = ABUF +  9600000;            // pname0 12000*160 = 1.92M
  PAD[3] = ABUF + 11520000;            // atac1  25000*288 = 7.20M
  PAD[4] = ABUF + 18720000;            // gene1  15000*160 = 2.40M (ends 21.12M < 35.3M)

  long gbaseT[5];
  {
    long o = 0;
    for (int g = 0; g < 5; g++) { gbaseT[g] = o; o += (long)128 * GPITCH[g]; }
  }
  int* POSg[5];
  {
    int o = 0;
    for (int g = 0; g < 5; g++) { POSg[g] = POSB + o; o += NT[GD[g]]; }
  }

  // 1) weight prep + POS permutation
  {
    WTStackArgs wa{};
    int j = 0;
    for (int g = 0; g < 5; g++) {
      wa.gnr[g] = GNR[g];
      for (int i = 0; i < 6; i++) wa.grel[g][i] = GRELS[g][i];
      for (int s = 0; s <= GNR[g]; s++, j++) {
        wa.srcrel[j] = (s < GNR[g]) ? GRELS[g][s] : -1;
        wa.grp[j] = g;
        wa.outoff[j] = gbaseT[g];
        wa.koff[j] = s * 128;
        wa.pitch[j] = GPITCH[g];
      }
    }
    hipLaunchKernelGGL(wtstack_kernel, dim3(64, 23), dim3(256), 0, stream,
                       conv_wl, conv_wr, conv_bl, WTG, BLS, wa);
  }
  {
    WTArgs pa{};
    int s = 0;
    auto add = [&](const float* W, u16* o, int K, int N, int Kpad) {
      pa.W[s] = W; pa.out[s] = o; pa.K[s] = K; pa.N[s] = N; pa.Kpad[s] = Kpad; s++;
    };
    add(W_in_atac,  WTIA, 257, 128, 288);
    add(W_in_gene,  WTIG, 129, 128, 160);
    add(W_in_pname, WTIP, 129, 128, 160);
    for (int g = 0; g < 5; g++) {
      int d = GD[g];
      add(mlp_w1 + (long)d * 128 * 256, WTM1 + (long)g * 32768, 128, 256, 128);
      add(mlp_w2 + (long)d * 256 * 128, WTM2 + (long)g * 32768, 256, 128, 256);
    }
    add(gd_w1, WTHD, 128, 256, 128);
    add(gv_w1, WTHV, 128, 256, 128);
    hipLaunchKernelGGL(wt_kernel, dim3(144, 15), dim3(256), 0, stream, pa);
  }
  {
    PosArgs pa{};
    for (int g = 0; g < 5; g++) {
      int d = GD[g];
      pa.m0[g] = mapin(d, 0); pa.m1[g] = mapin(d, 1); pa.pos[g] = POSg[g]; pa.n[g] = NT[d];
    }
    hipLaunchKernelGGL(pos_kernel, dim3(98, 5), dim3(256), 0, stream, pa);
  }

  // 2) all fp32->bf16 converts in ONE launch + batched input-linear GEMMs
  {
    PadArgs pc{};
    auto addp = [&](int s, const float* src, u16* dst, int M, int K, int Kpad) {
      pc.src[s] = src; pc.dst[s] = dst; pc.K[s] = K;
      pc.Kpad8[s] = Kpad / 8; pc.total[s] = M * (Kpad / 8);
      pc.aligned[s] = ((K & 7) == 0) ? 1 : 0;
    };
    addp(0, xin(0,0), PAD[0], 25000, 257, 288);
    addp(1, xin(1,0), PAD[1], 15000, 129, 160);
    addp(2, xin(4,0), PAD[2], 12000, 129, 160);
    addp(3, xin(0,1), PAD[3], 25000, 257, 288);
    addp(4, xin(1,1), PAD[4], 15000, 129, 160);
    addp(5, xin(2,0), XB0[2],  4000, 128, 128);
    addp(6, xin(3,0), XB0[3], 12000, 128, 128);
    addp(7, xin(5,0), XB0[5], 15000, 128, 128);
    addp(8, xin(2,1), XB1[2],  4000, 128, 128);
    addp(9, xin(3,1), XB1[3], 12000, 128, 128);
    addp(10, xin(5,1), XB1[5], 15000, 128, 128);
    hipLaunchKernelGGL(padcvt_kernel, dim3(3516, 11), dim3(256), 0, stream, pc);

    InLinBArgs ia{};
    auto add = [&](int s, const u16* A, const u16* WT, const float* b, u16* C,
                   int M, int Kpad) {
      ia.A[s] = A; ia.WT[s] = WT; ia.bias[s] = b; ia.C[s] = C;
      ia.M[s] = M; ia.Kpad[s] = Kpad;
    };
    add(0, PAD[0], WTIA, b_in_atac,  XB0[0], 25000, 288);
    add(1, PAD[1], WTIG, b_in_gene,  XB0[1], 15000, 160);
    add(2, PAD[2], WTIP, b_in_pname, XB0[4], 12000, 160);
    add(3, PAD[3], WTIA, b_in_atac,  XB1[0], 25000, 288);
    add(4, PAD[4], WTIG, b_in_gene,  XB1[1], 15000, 160);
    hipLaunchKernelGGL(tgemm_inb, dim3(391, 1, 5), dim3(256), 0, stream, ia);
  }

  // 3) CSR build (combined L0 18 + L1 6 slots)
  static const int L0R[18] = {0,1,2,3,4,5,6,7,8,9,10,12,13,14,15,16,17,18};
  static const int L1R[6]  = {2, 4, 7, 9, 15, 17};
  int rpoffByRel[19], slotByRel[19], rpoff1[19], slot1[19];
  CsrArgs cc{};
  {
    int ro = 0, bo = 0, s = 0;
    for (int i = 0; i < 18; i++, s++) {
      int r = L0R[i];
      cc.relid[s] = r; cc.lay[s] = 0; int nd = NT[REL_D[r]];
      cc.nd[s] = nd; cc.rpoff[s] = ro;
      cc.bkoff[s] = bo; cc.bboff[s] = bo + s; cc.nb[s] = (nd + 127) >> 7;
      rpoffByRel[r] = ro; slotByRel[r] = s;
      ro += nd + 1; bo += cc.nb[s];
    }
    for (int i = 0; i < 6; i++, s++) {
      int r = L1R[i];
      cc.relid[s] = r; cc.lay[s] = 1;
      cc.nd[s] = 15000; cc.rpoff[s] = ro;
      cc.bkoff[s] = bo; cc.bboff[s] = bo + s; cc.nb[s] = (15000 + 127) >> 7;
      rpoff1[r] = ro; slot1[r] = s;
      ro += 15001; bo += cc.nb[s];
    }
    hipMemsetAsync(BCNT, 0, (size_t)bo * 4, stream);
    hipLaunchKernelGGL(bhist_kernel, dim3(24 * 25), dim3(256), 0, stream, edges0, edges1, BCNT, cc);
    hipLaunchKernelGGL(bscan_kernel, dim3(24), dim3(256), 0, stream, BCNT, BBASE, BCUR, cc);
    hipLaunchKernelGGL(bucket_scatter, dim3(24 * 25), dim3(256), 0, stream,
                       edges0, edges1, BCUR, TMP, cc);
    hipLaunchKernelGGL(bucket_to_csr, dim3(196, 24), dim3(256), 0, stream, TMP, BBASE, RP, ESRC, cc);
  }

  // 4) agg (18 gathered slots) -> fused conv+MLP1+MLP2+scatter (z=5)
  {
    AggAllArgs aa{};
    int j = 0;
    for (int g = 0; g < 5; g++) {
      int d = GD[g];
      for (int i = 0; i < GNR[g]; i++, j++) {
        int r = GRELS[g][i];
        aa.xsrc[j]   = XB0[REL_S[r]];
        aa.rowptr[j] = RP + rpoffByRel[r];
        aa.esrc[j]   = ESRC + (long)slotByRel[r] * E_EDGES;
        aa.dst[j] = ABUFg[g]; aa.nd[j] = NT[d]; aa.pitch[j] = GPA[g];
        aa.koff[j] = i * 128;
      }
    }
    hipLaunchKernelGGL(agg_all, dim3(1563, 18), dim3(256), 0, stream, aa);
  }
  {
    FusedArgs fa{};
    for (int g = 0; g < 5; g++) {
      int d = GD[g];
      fa.A[g] = ABUFg[g]; fa.selfA[g] = XB0[d];
      fa.WTC[g] = WTG + gbaseT[g]; fa.biasC[g] = BLS + g * 128;
      fa.W1[g] = WTM1 + (long)g * 32768; fa.b1[g] = mlp_b1 + d * 256;
      fa.W2[g] = WTM2 + (long)g * 32768; fa.b2[g] = mlp_b2 + d * 128;
      fa.POS[g] = POSg[g]; fa.C[g] = XB1[d];
      fa.M[g] = NT[d]; fa.kself[g] = GPA[g]; fa.Kpad[g] = GPITCH[g];
    }
    hipLaunchKernelGGL(fused_mlp, dim3(391, 1, 5), dim3(256), 0, stream, fa);
  }

  // 5) layer-1 gene conv: agg (6 slots) + conv (direct self) -> G1B (bf16)
  {
    AggAllArgs aa{};
    for (int i = 0; i < 6; i++) {
      int r = L1R[i];
      aa.xsrc[i]   = XB1[REL_S[r]];
      aa.rowptr[i] = RP + rpoff1[r];
      aa.esrc[i]   = ESRC + (long)slot1[r] * E_EDGES;
      aa.dst[i] = ABUF; aa.nd[i] = 15000; aa.pitch[i] = 768;
      aa.koff[i] = i * 128;
    }
    hipLaunchKernelGGL(agg_all, dim3(938, 6), dim3(256), 0, stream, aa);
    hipLaunchKernelGGL(conv_l1, dim3(235), dim3(256), 0, stream,
                       ABUF, XB1[1], WTG + gbaseT[1], BLS + 1 * 128, G1B,
                       15000, 768, 896);
  }

  // 6) gene heads: batched MFMA (z=2, bf16 A) + batched reduce
  {
    HeadArgs ha{};
    ha.WT[0] = WTHD; ha.WT[1] = WTHV;
    ha.b1[0] = gd_b1; ha.b1[1] = gv_b1;
    ha.hid[0] = HIDF0; ha.hid[1] = HIDF1;
    ha.A = G1B; ha.M = 15000;
    hipLaunchKernelGGL(tgemm_head, dim3(235, 2, 2), dim3(256), 0, stream, ha);
    HeadRArgs hr{};
    hr.hid[0] = HIDF0; hr.hid[1] = HIDF1;
    hr.w2[0] = gd_w2; hr.w2[1] = gv_w2;
    hr.b2[0] = gd_b2; hr.b2[1] = gv_b2;
    hr.out = out; hr.M = 15000;
    hipLaunchKernelGGL(head_reduce2, dim3(3750, 2), dim3(256), 0, stream, hr);
  }
}

// Round 8
// 517.626 us; speedup vs baseline: 1.2845x; 1.0161x over previous
//
#include <hip/hip_runtime.h>
#include <math.h>

#define E_EDGES 100000

typedef unsigned short u16;
typedef unsigned int u32;

using bfrag = __attribute__((ext_vector_type(8))) short;
using ffrag = __attribute__((ext_vector_type(4))) float;

__device__ inline float bf2f(u32 u) { union { u32 i; float f; } c; c.i = u << 16; return c.f; }
__device__ inline u16 f2bf(float f) {
  union { u32 i; float f; } c; c.f = f;
  u32 u = c.i;
  return (u16)((u + 0x7FFFu + ((u >> 16) & 1u)) >> 16);
}

// ---------------- structs ----------------
struct CsrArgs { int relid[24]; int lay[24]; int nd[24]; int rpoff[24];
                 int bkoff[24]; int bboff[24]; int nb[24]; };

struct AggAllArgs {
  const u16* xsrc[18];
  const int* rowptr[18];
  const int* esrc[18];
  u16* dst[18];
  int nd[18]; int pitch[18]; int koff[18];
};

struct WTStackArgs {
  int srcrel[23]; int grp[23]; long outoff[23]; int koff[23]; int pitch[23];
  int gnr[5]; int grel[5][6];
};

struct WTArgs { const float* W[15]; u16* out[15]; int K[15]; int N[15]; int Kpad[15]; };
struct PadArgs { const float* src[11]; u16* dst[11]; int K[11]; int Kpad8[11];
                 int total[11]; int aligned[11]; };
struct InLinBArgs { const u16* A[5]; const u16* WT[5]; const float* bias[5]; u16* C[5];
                    int M[5]; int Kpad[5]; };
struct FusedArgs {
  const u16* A[5]; const u16* selfA[5]; const u16* WTC[5]; const float* biasC[5];
  const u16* W1[5]; const float* b1[5]; const u16* W2[5]; const float* b2[5];
  const int* POS[5]; u16* C[5]; int M[5]; int kself[5]; int Kpad[5];
};
struct PosArgs { const int* m0[5]; const int* m1[5]; int* pos[5]; int n[5]; };
struct HeadArgs { const u16* WT[2]; const float* b1[2]; float* hid[2]; const u16* A; int M; };
struct HeadRArgs { const float* hid[2]; const float* w2[2]; const float* b2[2]; float* out; int M; };

// ---------------- batched bf16 GEMM (input linears), N=128 ------------
__global__ __launch_bounds__(256) void tgemm_inb(InLinBArgs a)
{
  const int z = blockIdx.z;
  const int M = a.M[z], Kpad = a.Kpad[z];
  const int rowbase = blockIdx.x * 64;
  if (rowbase >= M) return;
  __shared__ u16 sA[64 * 40];
  __shared__ u16 sB[128 * 40];
  const int tid = threadIdx.x;
  const int w = tid >> 6, lane = tid & 63;
  const int quad = lane >> 4, m = lane & 15;
  const int sr = tid >> 2, sc = tid & 3;
  const int br = tid >> 1, bh = tid & 1;
  const u16* A = a.A[z];
  const u16* WT = a.WT[z];
  ffrag acc[8];
  #pragma unroll
  for (int i = 0; i < 8; i++) { acc[i][0] = 0.f; acc[i][1] = 0.f; acc[i][2] = 0.f; acc[i][3] = 0.f; }

  for (int kt = 0; kt < Kpad / 32; kt++) {
    int gr = rowbase + sr, gk = kt * 32 + sc * 8;
    uint4 st = make_uint4(0, 0, 0, 0);
    if (gr < M) st = *(const uint4*)(A + (long)gr * Kpad + gk);
    const u16* wrow = WT + (long)br * Kpad + kt * 32 + bh * 16;
    uint4 b0 = *(const uint4*)wrow;
    uint4 b1 = *(const uint4*)(wrow + 8);

    if (kt) __syncthreads();
    *(uint4*)&sA[sr * 40 + sc * 8] = st;
    *(uint4*)&sB[br * 40 + bh * 16] = b0;
    *(uint4*)&sB[br * 40 + bh * 16 + 8] = b1;
    __syncthreads();

    bfrag av = *(const bfrag*)&sA[(w * 16 + m) * 40 + quad * 8];
    #pragma unroll
    for (int ct = 0; ct < 8; ct++) {
      bfrag bv = *(const bfrag*)&sB[(ct * 16 + m) * 40 + quad * 8];
      acc[ct] = __builtin_amdgcn_mfma_f32_16x16x32_bf16(av, bv, acc[ct], 0, 0, 0);
    }
  }

  const float* bias = a.bias[z];
  u16* C = a.C[z];
  #pragma unroll
  for (int ct = 0; ct < 8; ct++) {
    int col = ct * 16 + m;
    float bv = bias[col];
    #pragma unroll
    for (int r = 0; r < 4; r++) {
      int row = rowbase + w * 16 + quad * 4 + r;
      if (row < M) C[(long)row * 128 + col] = f2bf(acc[ct][r] + bv);
    }
  }
}

// ------- fused conv + MLP1(relu) + MLP2 + POS-scatter (per dst group, z-batched) -----
// Round-5 structure (MSTR=136, verified 519us total) + stage-1 register prefetch:
// next-kt A/B global loads are issued BEFORE the current kt's barriers+MFMA so the
// ~600-900cy HBM latency of the ABUF stream overlaps compute instead of serializing
// (only ~2 blocks/CU resident -> wave-level TLP cannot hide it implicitly).
// LDS overlay (u16): sB[0,5120) sA[5120,7680) m1[7680,16384)
//                    m2b[5120,13824) (after m1 dead)  m2a[16384,25088)
#define MSTR 136
__global__ __launch_bounds__(256) void fused_mlp(FusedArgs a)
{
  const int z = blockIdx.z;
  const int M = a.M[z];
  const int rowbase = blockIdx.x * 64;
  if (rowbase >= M) return;
  __shared__ u16 LDS[25088];
  u16* sB  = LDS;
  u16* sA  = LDS + 5120;
  u16* m1  = LDS + 7680;   // 64 x 136
  u16* m2b = LDS + 5120;   // 64 x 136 (overlays sA + head of m1)
  u16* m2a = LDS + 16384;  // 64 x 136
  const int tid = threadIdx.x;
  const int w = tid >> 6, lane = tid & 63;
  const int quad = lane >> 4, m = lane & 15;
  const int sr = tid >> 2, sc = tid & 3;
  const int br = tid >> 1, bh = tid & 1;
  const int kself = a.kself[z], Kpad = a.Kpad[z];
  const u16* A = a.A[z];
  const u16* selfA = a.selfA[z];

  // ---- stage 1: conv GEMM with register-prefetched global loads ----
  {
    const u16* WT = a.WTC[z];
    const int nk = Kpad / 32;
    ffrag acc[8];
    #pragma unroll
    for (int i = 0; i < 8; i++) { acc[i][0] = 0.f; acc[i][1] = 0.f; acc[i][2] = 0.f; acc[i][3] = 0.f; }

    auto loadA = [&](int kt) -> uint4 {
      int gr = rowbase + sr, gk = kt * 32 + sc * 8;
      uint4 v = make_uint4(0, 0, 0, 0);
      if (gr < M) {
        const u16* src = (gk < kself) ? (A + (long)gr * kself + gk)
                                      : (selfA + (long)gr * 128 + (gk - kself));
        v = *(const uint4*)src;
      }
      return v;
    };

    uint4 st = loadA(0);
    const u16* wrow0 = WT + (long)br * Kpad + bh * 16;
    uint4 b0 = *(const uint4*)wrow0;
    uint4 b1 = *(const uint4*)(wrow0 + 8);

    for (int kt = 0; kt < nk; kt++) {
      uint4 stn = st, b0n = b0, b1n = b1;
      if (kt + 1 < nk) {
        stn = loadA(kt + 1);                        // issue early: hides under MFMA
        const u16* wrow = WT + (long)br * Kpad + (kt + 1) * 32 + bh * 16;
        b0n = *(const uint4*)wrow;
        b1n = *(const uint4*)(wrow + 8);
      }
      if (kt) __syncthreads();
      *(uint4*)&sA[sr * 40 + sc * 8] = st;
      *(uint4*)&sB[br * 40 + bh * 16] = b0;
      *(uint4*)&sB[br * 40 + bh * 16 + 8] = b1;
      __syncthreads();

      bfrag av = *(const bfrag*)&sA[(w * 16 + m) * 40 + quad * 8];
      #pragma unroll
      for (int ct = 0; ct < 8; ct++) {
        bfrag bv = *(const bfrag*)&sB[(ct * 16 + m) * 40 + quad * 8];
        acc[ct] = __builtin_amdgcn_mfma_f32_16x16x32_bf16(av, bv, acc[ct], 0, 0, 0);
      }
      st = stn; b0 = b0n; b1 = b1n;
    }
    // conv epilogue -> m1 (bf16 + bias); m1 is disjoint from sA/sB, no barrier needed yet
    const float* bc = a.biasC[z];
    #pragma unroll
    for (int ct = 0; ct < 8; ct++) {
      int col = ct * 16 + m;
      float bv = bc[col];
      #pragma unroll
      for (int r = 0; r < 4; r++) {
        int row = w * 16 + quad * 4 + r;
        m1[row * MSTR + col] = f2bf(acc[ct][r] + bv);
      }
    }
  }

  // ---- stage 2: MLP1 (K=128 from m1, N=256 in two col-halves, relu) ----
  {
    const u16* W1 = a.W1[z];
    const float* b1p = a.b1[z];
    for (int h = 0; h < 2; h++) {
      ffrag acch[8];
      #pragma unroll
      for (int i = 0; i < 8; i++) { acch[i][0] = 0.f; acch[i][1] = 0.f; acch[i][2] = 0.f; acch[i][3] = 0.f; }
      for (int kt = 0; kt < 4; kt++) {
        const u16* wrow = W1 + (long)(h * 128 + br) * 128 + kt * 32 + bh * 16;
        uint4 b0 = *(const uint4*)wrow;
        uint4 b1v = *(const uint4*)(wrow + 8);
        __syncthreads();                    // prior sB readers done; m1 visible (1st iter)
        *(uint4*)&sB[br * 40 + bh * 16] = b0;
        *(uint4*)&sB[br * 40 + bh * 16 + 8] = b1v;
        __syncthreads();
        bfrag av = *(const bfrag*)&m1[(w * 16 + m) * MSTR + kt * 32 + quad * 8];
        #pragma unroll
        for (int ct = 0; ct < 8; ct++) {
          bfrag bv = *(const bfrag*)&sB[(ct * 16 + m) * 40 + quad * 8];
          acch[ct] = __builtin_amdgcn_mfma_f32_16x16x32_bf16(av, bv, acch[ct], 0, 0, 0);
        }
      }
      u16* dstm = h ? m2b : m2a;
      if (h) __syncthreads();               // m2b overlays m1: all m1 readers must be done
      #pragma unroll
      for (int ct = 0; ct < 8; ct++) {
        int col = ct * 16 + m;
        float bv = b1p[h * 128 + col];
        #pragma unroll
        for (int r = 0; r < 4; r++) {
          int row = w * 16 + quad * 4 + r;
          dstm[row * MSTR + col] = f2bf(fmaxf(acch[ct][r] + bv, 0.f));
        }
      }
    }
  }

  // ---- stage 3: MLP2 (K=256 from m2a/m2b, N=128) + POS scatter ----
  {
    const u16* W2 = a.W2[z];
    ffrag acc2[8];
    #pragma unroll
    for (int i = 0; i < 8; i++) { acc2[i][0] = 0.f; acc2[i][1] = 0.f; acc2[i][2] = 0.f; acc2[i][3] = 0.f; }
    for (int kt = 0; kt < 8; kt++) {
      const u16* wrow = W2 + (long)br * 256 + kt * 32 + bh * 16;
      uint4 b0 = *(const uint4*)wrow;
      uint4 b1v = *(const uint4*)(wrow + 8);
      __syncthreads();                      // prior sB readers done; m2b visible (1st iter)
      *(uint4*)&sB[br * 40 + bh * 16] = b0;
      *(uint4*)&sB[br * 40 + bh * 16 + 8] = b1v;
      __syncthreads();
      const u16* msrc = (kt < 4) ? m2a : m2b;
      bfrag av = *(const bfrag*)&msrc[(w * 16 + m) * MSTR + (kt & 3) * 32 + quad * 8];
      #pragma unroll
      for (int ct = 0; ct < 8; ct++) {
        bfrag bv = *(const bfrag*)&sB[(ct * 16 + m) * 40 + quad * 8];
        acc2[ct] = __builtin_amdgcn_mfma_f32_16x16x32_bf16(av, bv, acc2[ct], 0, 0, 0);
      }
    }
    const int* POS = a.POS[z];
    const float* b2p = a.b2[z];
    u16* C = a.C[z];
    #pragma unroll
    for (int ct = 0; ct < 8; ct++) {
      int col = ct * 16 + m;
      float bv = b2p[col];
      #pragma unroll
      for (int r = 0; r < 4; r++) {
        int row = rowbase + w * 16 + quad * 4 + r;
        if (row < M) {
          int j = POS[row];
          if (j >= 0) C[(long)j * 128 + col] = f2bf(acc2[ct][r] + bv);
        }
      }
    }
  }
}

// ---------------- L1 gene conv: gathered A + direct self, bf16 out ----------------
__global__ __launch_bounds__(256) void conv_l1(const u16* __restrict__ A,
                                               const u16* __restrict__ selfA,
                                               const u16* __restrict__ WT,
                                               const float* __restrict__ bias,
                                               u16* __restrict__ C,
                                               int M, int kself, int Kpad)
{
  const int rowbase = blockIdx.x * 64;
  if (rowbase >= M) return;
  __shared__ u16 sA[64 * 40];
  __shared__ u16 sB[128 * 40];
  const int tid = threadIdx.x;
  const int w = tid >> 6, lane = tid & 63;
  const int quad = lane >> 4, m = lane & 15;
  const int sr = tid >> 2, sc = tid & 3;
  const int br = tid >> 1, bh = tid & 1;
  ffrag acc[8];
  #pragma unroll
  for (int i = 0; i < 8; i++) { acc[i][0] = 0.f; acc[i][1] = 0.f; acc[i][2] = 0.f; acc[i][3] = 0.f; }

  for (int kt = 0; kt < Kpad / 32; kt++) {
    int gr = rowbase + sr, gk = kt * 32 + sc * 8;
    uint4 st = make_uint4(0, 0, 0, 0);
    if (gr < M) {
      const u16* src = (gk < kself) ? (A + (long)gr * kself + gk)
                                    : (selfA + (long)gr * 128 + (gk - kself));
      st = *(const uint4*)src;
    }
    const u16* wrow = WT + (long)br * Kpad + kt * 32 + bh * 16;
    uint4 b0 = *(const uint4*)wrow;
    uint4 b1 = *(const uint4*)(wrow + 8);

    if (kt) __syncthreads();
    *(uint4*)&sA[sr * 40 + sc * 8] = st;
    *(uint4*)&sB[br * 40 + bh * 16] = b0;
    *(uint4*)&sB[br * 40 + bh * 16 + 8] = b1;
    __syncthreads();

    bfrag av = *(const bfrag*)&sA[(w * 16 + m) * 40 + quad * 8];
    #pragma unroll
    for (int ct = 0; ct < 8; ct++) {
      bfrag bv = *(const bfrag*)&sB[(ct * 16 + m) * 40 + quad * 8];
      acc[ct] = __builtin_amdgcn_mfma_f32_16x16x32_bf16(av, bv, acc[ct], 0, 0, 0);
    }
  }

  #pragma unroll
  for (int ct = 0; ct < 8; ct++) {
    int col = ct * 16 + m;
    float bv = bias[col];
    #pragma unroll
    for (int r = 0; r < 4; r++) {
      int row = rowbase + w * 16 + quad * 4 + r;
      if (row < M) C[(long)row * 128 + col] = f2bf(acc[ct][r] + bv);
    }
  }
}

// ---------------- streaming fp32 -> padded bf16 convert (11 slots, one launch) -------
__global__ __launch_bounds__(256) void padcvt_kernel(PadArgs a)
{
  const int z = blockIdx.y;
  int idx = blockIdx.x * 256 + threadIdx.x;
  if (idx >= a.total[z]) return;
  const int kp8 = a.Kpad8[z];
  const int K = a.K[z];
  int row = idx / kp8;
  int c8 = idx - row * kp8;
  int base = c8 * 8;
  u32 wv[4];
  if (a.aligned[z]) {
    const float4* src = (const float4*)(a.src[z] + (long)row * K + base);
    float4 f0 = src[0];
    float4 f1 = src[1];
    wv[0] = (u32)f2bf(f0.x) | ((u32)f2bf(f0.y) << 16);
    wv[1] = (u32)f2bf(f0.z) | ((u32)f2bf(f0.w) << 16);
    wv[2] = (u32)f2bf(f1.x) | ((u32)f2bf(f1.y) << 16);
    wv[3] = (u32)f2bf(f1.z) | ((u32)f2bf(f1.w) << 16);
  } else {
    const float* src = a.src[z] + (long)row * K + base;
    #pragma unroll
    for (int i = 0; i < 4; i++) {
      float lo = (base + 2 * i     < K) ? src[2 * i]     : 0.f;
      float hi = (base + 2 * i + 1 < K) ? src[2 * i + 1] : 0.f;
      wv[i] = (u32)f2bf(lo) | ((u32)f2bf(hi) << 16);
    }
  }
  *(uint4*)(a.dst[z] + (long)row * (kp8 * 8) + base) = make_uint4(wv[0], wv[1], wv[2], wv[3]);
}

// ---------------- batched gene heads (bf16 A, fp32 out, relu, N=256) ----------------
__global__ __launch_bounds__(256) void tgemm_head(HeadArgs a)
{
  const int z = blockIdx.z;
  const int M = a.M;
  const int rowbase = blockIdx.x * 64;
  const int colbase = blockIdx.y * 128;
  __shared__ u16 sA[64 * 40];
  __shared__ u16 sB[128 * 40];
  const int tid = threadIdx.x;
  const int w = tid >> 6, lane = tid & 63;
  const int quad = lane >> 4, m = lane & 15;
  const int sr = tid >> 2, sc = tid & 3;
  const int br = tid >> 1, bh = tid & 1;
  const u16* A = a.A;
  const u16* WT = a.WT[z];
  ffrag acc[8];
  #pragma unroll
  for (int i = 0; i < 8; i++) { acc[i][0] = 0.f; acc[i][1] = 0.f; acc[i][2] = 0.f; acc[i][3] = 0.f; }

  for (int kt = 0; kt < 4; kt++) {
    int gr = rowbase + sr, gk = kt * 32 + sc * 8;
    uint4 st = make_uint4(0, 0, 0, 0);
    if (gr < M) st = *(const uint4*)(A + (long)gr * 128 + gk);
    const u16* wrow = WT + (long)(colbase + br) * 128 + kt * 32 + bh * 16;
    uint4 b0 = *(const uint4*)wrow;
    uint4 b1 = *(const uint4*)(wrow + 8);

    if (kt) __syncthreads();
    *(uint4*)&sA[sr * 40 + sc * 8] = st;
    *(uint4*)&sB[br * 40 + bh * 16] = b0;
    *(uint4*)&sB[br * 40 + bh * 16 + 8] = b1;
    __syncthreads();

    bfrag av = *(const bfrag*)&sA[(w * 16 + m) * 40 + quad * 8];
    #pragma unroll
    for (int ct = 0; ct < 8; ct++) {
      bfrag bv = *(const bfrag*)&sB[(ct * 16 + m) * 40 + quad * 8];
      acc[ct] = __builtin_amdgcn_mfma_f32_16x16x32_bf16(av, bv, acc[ct], 0, 0, 0);
    }
  }

  const float* bias = a.b1[z];
  float* C = a.hid[z];
  #pragma unroll
  for (int ct = 0; ct < 8; ct++) {
    int col = colbase + ct * 16 + m;
    float bv = bias[col];
    #pragma unroll
    for (int r = 0; r < 4; r++) {
      int row = rowbase + w * 16 + quad * 4 + r;
      if (row < M) C[(long)row * 256 + col] = fmaxf(acc[ct][r] + bv, 0.f);
    }
  }
}

// ---------------- CSR build: bucket-level histogram (LDS-privatized) ----------------
__global__ __launch_bounds__(256) void bhist_kernel(const int* __restrict__ e0,
                                                    const int* __restrict__ e1,
                                                    int* __restrict__ bcnt, CsrArgs a)
{
  const int slot = blockIdx.x / 25;
  const int ch = blockIdx.x % 25;
  const int base = ch * 4096;
  const int n = (E_EDGES - base < 4096) ? (E_EDGES - base) : 4096;
  const int* E = a.lay[slot] ? e1 : e0;
  const int r = a.relid[slot];
  const int tid = threadIdx.x;
  __shared__ int h[256];
  h[tid] = 0;
  __syncthreads();
  const int* darr = E + (r * 2 + 1) * E_EDGES + base;
  for (int i = tid; i < n; i += 256) atomicAdd(&h[darr[i] >> 7], 1);
  __syncthreads();
  if (tid < a.nb[slot] && h[tid]) atomicAdd(&bcnt[a.bkoff[slot] + tid], h[tid]);
}

// per-slot scan of bucket counts -> bucket bases (exclusive, + sentinel) and cursors
__global__ __launch_bounds__(256) void bscan_kernel(const int* __restrict__ bcnt,
                                                    int* __restrict__ bbase,
                                                    int* __restrict__ bcur, CsrArgs a)
{
  int slot = blockIdx.x;
  int nb = a.nb[slot];
  int tid = threadIdx.x, lane = tid & 63, w = tid >> 6;
  __shared__ int ws[4];
  int v = (tid < nb) ? bcnt[a.bkoff[slot] + tid] : 0;
  int si = v;
  #pragma unroll
  for (int off = 1; off < 64; off <<= 1) {
    int t = __shfl_up(si, off, 64);
    if (lane >= off) si += t;
  }
  if (lane == 63) ws[w] = si;
  __syncthreads();
  int woff = 0;
  #pragma unroll
  for (int k = 0; k < 4; k++) if (k < w) woff += ws[k];
  int excl = woff + si - v;
  if (tid < nb) { bbase[a.bboff[slot] + tid] = excl; bcur[a.bkoff[slot] + tid] = excl; }
  if (tid == 0) bbase[a.bboff[slot] + nb] = ws[0] + ws[1] + ws[2] + ws[3];
}

// pass B: per-block LDS bucketing + coalesced burst append into TMP
__global__ __launch_bounds__(256) void bucket_scatter(const int* __restrict__ e0,
                                                      const int* __restrict__ e1,
                                                      int* __restrict__ bcur,
                                                      u32* __restrict__ tmp, CsrArgs a)
{
  const int slot = blockIdx.x / 25;
  const int ch = blockIdx.x % 25;
  const int base = ch * 4096;
  const int n = (E_EDGES - base < 4096) ? (E_EDGES - base) : 4096;
  const int* E = a.lay[slot] ? e1 : e0;
  const int r = a.relid[slot];
  const int nb = a.nb[slot];
  const int tid = threadIdx.x;
  __shared__ int hist[256], start[256], gbase[256], lcur[256];
  __shared__ u32 sorted[4096];
  hist[tid] = 0;
  __syncthreads();
  const int* darr = E + (r * 2 + 1) * E_EDGES + base;
  const int* sarr = E + r * 2 * E_EDGES + base;
  for (int i = tid; i < n; i += 256) atomicAdd(&hist[darr[i] >> 7], 1);
  __syncthreads();
  if (tid == 0) {
    int s = 0;
    for (int b = 0; b < nb; b++) { start[b] = s; s += hist[b]; }
  }
  __syncthreads();
  if (tid < nb) {
    gbase[tid] = atomicAdd(&bcur[a.bkoff[slot] + tid], hist[tid]);
    lcur[tid] = start[tid];
  }
  __syncthreads();
  for (int i = tid; i < n; i += 256) {
    int dst = darr[i], src = sarr[i];
    int pos = atomicAdd(&lcur[dst >> 7], 1);
    sorted[pos] = ((u32)dst << 16) | (u32)src;
  }
  __syncthreads();
  u32* out = tmp + (long)slot * E_EDGES;
  for (int i = tid; i < n; i += 256) {
    u32 p = sorted[i];
    int b = p >> 23;
    out[gbase[b] + (i - start[b])] = p;
  }
}

// pass C: per-(slot,bucket): derive rowptr segment + LDS counting-sort into CSR
__global__ __launch_bounds__(256) void bucket_to_csr(const u32* __restrict__ tmp,
                                                     const int* __restrict__ bbase,
                                                     int* __restrict__ rp,
                                                     int* __restrict__ esrc, CsrArgs a)
{
  const int b = blockIdx.x, slot = blockIdx.y;
  if (b >= a.nb[slot]) return;
  const int rb = a.rpoff[slot];
  const int bb = bbase[a.bboff[slot] + b];
  const int be = bbase[a.bboff[slot] + b + 1];
  const int cnt = be - bb;
  const int rowlo = b << 7;
  int rowhi = rowlo + 128; if (rowhi > a.nd[slot]) rowhi = a.nd[slot];
  const int nrow = rowhi - rowlo;
  const int tid = threadIdx.x;
  __shared__ int rcnt[128];
  __shared__ int rpref[129];
  __shared__ int scur[128];
  __shared__ u32 sbuf[8192];
  if (tid < 128) rcnt[tid] = 0;
  __syncthreads();
  const u32* in = tmp + (long)slot * E_EDGES + bb;
  for (int i = tid; i < cnt; i += 256) atomicAdd(&rcnt[(in[i] >> 16) & 127], 1);
  __syncthreads();
  if (tid == 0) {
    int s = 0;
    for (int t = 0; t < 128; t++) { rpref[t] = s; s += rcnt[t]; }
    rpref[128] = s;
  }
  __syncthreads();
  if (tid < nrow) rp[rb + rowlo + tid] = bb + rpref[tid];
  if (tid == 0) rp[rb + rowhi] = be;
  if (tid < 128) scur[tid] = rpref[tid];
  __syncthreads();
  int* out = esrc + (long)slot * E_EDGES + bb;
  if (cnt <= 8192) {
    for (int i = tid; i < cnt; i += 256) {
      u32 p = in[i];
      int pos = atomicAdd(&scur[(p >> 16) & 127], 1);
      sbuf[pos] = p & 0xFFFFu;
    }
    __syncthreads();
    for (int i = tid; i < cnt; i += 256) out[i] = (int)sbuf[i];
  } else {
    for (int i = tid; i < cnt; i += 256) {
      u32 p = in[i];
      int pos = atomicAdd(&scur[(p >> 16) & 127], 1);
      out[pos] = (int)(p & 0xFFFFu);
    }
  }
}

// ---------------- weight prep ----------------
__global__ __launch_bounds__(256) void wtstack_kernel(const float* __restrict__ wl,
                                                      const float* __restrict__ wr,
                                                      const float* __restrict__ bl,
                                                      u16* __restrict__ WTG,
                                                      float* __restrict__ BLS, WTStackArgs a)
{
  int slot = blockIdx.y;
  int t = blockIdx.x * 256 + threadIdx.x;
  int krel = t & 127, n = t >> 7;
  int sr = a.srcrel[slot];
  float v;
  if (sr >= 0) {
    v = wl[(long)sr * 16384 + krel * 128 + n];
  } else {
    int g = a.grp[slot];
    v = 0.f;
    for (int i = 0; i < a.gnr[g]; i++) v += wr[(long)a.grel[g][i] * 16384 + krel * 128 + n];
    if (t < 128) {
      float b = 0.f;
      for (int i = 0; i < a.gnr[g]; i++) b += bl[a.grel[g][i] * 128 + t];
      BLS[g * 128 + t] = b;
    }
  }
  WTG[a.outoff[slot] + (long)n * a.pitch[slot] + a.koff[slot] + krel] = f2bf(v);
}

__global__ __launch_bounds__(256) void wt_kernel(WTArgs a)
{
  int s = blockIdx.y;
  int idx = blockIdx.x * 256 + threadIdx.x;
  int K = a.K[s], N = a.N[s], Kpad = a.Kpad[s];
  if (idx >= N * Kpad) return;
  int n = idx / Kpad, k = idx - n * Kpad;
  a.out[s][idx] = (k < K) ? f2bf(a.W[s][(long)k * N + n]) : (u16)0;
}

__global__ __launch_bounds__(256) void pos_kernel(PosArgs a)
{
  int g = blockIdx.y;
  int i = blockIdx.x * 256 + threadIdx.x;
  if (i >= a.n[g]) return;
  int key = a.m0[g][i];
  const int* m1 = a.m1[g];
  int lo = 0, hi = a.n[g] - 1, pos = -1;
  while (lo <= hi) {
    int mid = (lo + hi) >> 1;
    int v = m1[mid];
    if (v == key) { pos = mid; break; }
    if (v < key) lo = mid + 1; else hi = mid - 1;
  }
  a.pos[g][i] = pos;
}

// ---------------- aggregation: 16 lanes/row, dwordx4 gathers, 4-deep unroll ---------
__global__ __launch_bounds__(256) void agg_all(AggAllArgs a)
{
  int slot = blockIdx.y;
  int grp = threadIdx.x >> 4;
  int lane = threadIdx.x & 15;
  int row = blockIdx.x * 16 + grp;
  if (row >= a.nd[slot]) return;
  u16* dst = a.dst[slot] + (long)row * a.pitch[slot] + a.koff[slot] + lane * 8;
  const uint4* x4 = (const uint4*)a.xsrc[slot];
  const int* rp = a.rowptr[slot];
  int c0 = rp[row], c1 = rp[row + 1];
  const int* es = a.esrc[slot];
  float acc[8];
  #pragma unroll
  for (int i = 0; i < 8; i++) acc[i] = 0.f;
  int e = c0;
  for (; e + 4 <= c1; e += 4) {
    int s0 = es[e], s1 = es[e + 1], s2 = es[e + 2], s3 = es[e + 3];
    uint4 v0 = x4[(long)s0 * 16 + lane];
    uint4 v1 = x4[(long)s1 * 16 + lane];
    uint4 v2 = x4[(long)s2 * 16 + lane];
    uint4 v3 = x4[(long)s3 * 16 + lane];
    const u32* w0 = (const u32*)&v0;
    const u32* w1 = (const u32*)&v1;
    const u32* w2 = (const u32*)&v2;
    const u32* w3 = (const u32*)&v3;
    #pragma unroll
    for (int i = 0; i < 4; i++) {
      acc[2*i]   += bf2f(w0[i] & 0xFFFF) + bf2f(w1[i] & 0xFFFF)
                  + bf2f(w2[i] & 0xFFFF) + bf2f(w3[i] & 0xFFFF);
      acc[2*i+1] += bf2f(w0[i] >> 16) + bf2f(w1[i] >> 16)
                  + bf2f(w2[i] >> 16) + bf2f(w3[i] >> 16);
    }
  }
  for (; e < c1; e++) {
    uint4 v = x4[(long)es[e] * 16 + lane];
    const u32* wv = (const u32*)&v;
    #pragma unroll
    for (int i = 0; i < 4; i++) {
      acc[2*i]   += bf2f(wv[i] & 0xFFFF);
      acc[2*i+1] += bf2f(wv[i] >> 16);
    }
  }
  int c = c1 - c0;
  float inv = 1.f / (float)(c > 1 ? c : 1);
  u32 o[4];
  #pragma unroll
  for (int i = 0; i < 4; i++)
    o[i] = (u32)f2bf(acc[2*i] * inv) | ((u32)f2bf(acc[2*i+1] * inv) << 16);
  *(uint4*)dst = make_uint4(o[0], o[1], o[2], o[3]);
}

// ---------------- batched head reduce (4 rows/block) ----------------
__global__ __launch_bounds__(256) void head_reduce2(HeadRArgs a)
{
  int wave = threadIdx.x >> 6, lane = threadIdx.x & 63;
  int row = blockIdx.x * 4 + wave;
  int z = blockIdx.y;
  if (row >= a.M) return;
  const float* h = a.hid[z] + (long)row * 256;
  const float* w2 = a.w2[z];
  float s = h[lane] * w2[lane] + h[lane + 64] * w2[lane + 64]
          + h[lane + 128] * w2[lane + 128] + h[lane + 192] * w2[lane + 192];
  #pragma unroll
  for (int off = 32; off >= 1; off >>= 1) s += __shfl_down(s, off, 64);
  if (lane == 0) {
    float v = s + a.b2[z][0];
    if (z == 0) v = 1.0f / (1.0f + expf(-v));
    a.out[row * 2 + z] = v;
  }
}

// ---------------- host orchestration ----------------
extern "C" void kernel_launch(void* const* d_in, const int* in_sizes, int n_in,
                              void* d_out, int out_size, void* d_ws, size_t ws_size,
                              hipStream_t stream)
{
  static const int NT[6] = {25000, 15000, 4000, 12000, 12000, 15000};
  static const int REL_S[19] = {2,0,2,1,0,1,3,3,1,3,1,3,4,5,0,5,1,0,1};
  static const int REL_D[19] = {0,2,1,2,1,0,3,1,3,1,3,4,3,0,5,1,5,1,0};

  auto xin   = [&](int t, int L) { return (const float*)d_in[L * 13 + 2 * t]; };
  auto mapin = [&](int t, int L) { return (const int*)d_in[L * 13 + 2 * t + 1]; };
  const int* edges0 = (const int*)d_in[12];
  const int* edges1 = (const int*)d_in[25];
  const float* W_in_atac  = (const float*)d_in[26];
  const float* b_in_atac  = (const float*)d_in[27];
  const float* W_in_gene  = (const float*)d_in[28];
  const float* b_in_gene  = (const float*)d_in[29];
  const float* W_in_pname = (const float*)d_in[30];
  const float* b_in_pname = (const float*)d_in[31];
  const float* conv_wl = (const float*)d_in[32];
  const float* conv_bl = (const float*)d_in[33];
  const float* conv_wr = (const float*)d_in[34];
  const float* mlp_w1 = (const float*)d_in[35];
  const float* mlp_b1 = (const float*)d_in[36];
  const float* mlp_w2 = (const float*)d_in[37];
  const float* mlp_b2 = (const float*)d_in[38];
  const float* gd_w1 = (const float*)d_in[39];
  const float* gd_b1 = (const float*)d_in[40];
  const float* gd_w2 = (const float*)d_in[41];
  const float* gd_b2 = (const float*)d_in[42];
  const float* gv_w1 = (const float*)d_in[43];
  const float* gv_b1 = (const float*)d_in[44];
  const float* gv_w2 = (const float*)d_in[45];
  const float* gv_b2 = (const float*)d_in[46];
  float* out = (float*)d_out;

  // dst-type groups
  static const int GD[5]       = {0, 1, 2, 3, 5};
  static const int GNR[5]      = {4, 6, 2, 4, 2};
  static const int GRELS[5][6] = {{0,5,13,18,0,0},{2,4,7,9,15,17},{1,3,0,0,0,0},
                                  {6,8,10,12,0,0},{14,16,0,0,0,0}};
  static const int GPITCH[5]   = {640, 896, 384, 640, 384};  // WTG K (incl. self 128)
  static const int GPA[5]      = {512, 768, 256, 512, 256};  // gathered-only pitch

  // ---- workspace carve ----
  float* fp = (float*)d_ws;
  auto takef = [&](size_t n) { float* q = fp; fp += n; return q; };
  float* BLS  = takef(5 * 128);
  u16* bp = (u16*)fp;
  auto takeb = [&](size_t n) { u16* q = bp; bp += n; return q; };
  u16* XB0[6]; u16* XB1[6];
  XB0[0] = takeb((size_t)25000 * 128);
  XB0[1] = takeb((size_t)15000 * 128);
  XB0[2] = takeb((size_t)4000 * 128);
  XB0[3] = takeb((size_t)12000 * 128);
  XB0[4] = takeb((size_t)12000 * 128);
  XB0[5] = takeb((size_t)15000 * 128);
  XB1[0] = takeb((size_t)25000 * 128);
  XB1[1] = takeb((size_t)15000 * 128);
  XB1[2] = takeb((size_t)4000 * 128);
  XB1[3] = takeb((size_t)12000 * 128);
  XB1[4] = nullptr;
  XB1[5] = takeb((size_t)15000 * 128);
  u16* ABUF = takeb((size_t)35328000);       // per-group gathered agg (no self)
  u16* ABUFg[5];
  {
    long o = 0;
    for (int g = 0; g < 5; g++) { ABUFg[g] = ABUF + o; o += (long)NT[GD[g]] * GPA[g]; }
  }
  u16* G1B  = takeb((size_t)15000 * 128);    // L1 conv out (bf16)
  u16* WTG  = takeb(376832);
  u16* WTIA = takeb(128 * 288);
  u16* WTIG = takeb(128 * 160);
  u16* WTIP = takeb(128 * 160);
  u16* WTM1 = takeb((size_t)5 * 32768);
  u16* WTM2 = takeb((size_t)5 * 32768);
  u16* WTHD = takeb(32768);
  u16* WTHV = takeb(32768);
  uintptr_t ipa = ((uintptr_t)bp + 15) & ~(uintptr_t)15;
  int* ip = (int*)ipa;
  auto takei = [&](size_t n) { int* q = ip; ip += n; return q; };
  int* RP    = takei(366024);
  int* BCNT  = takei(4704);
  int* BBASE = takei(4728);
  int* BCUR  = takei(4704);
  int* POSB  = takei(71000);
  int* ESRC  = takei((size_t)24 * E_EDGES);
  // aliases inside ABUF (disjoint lifetimes, in-order stream):
  u32* TMP = (u32*)ABUF;                         // CSR staging (phase 3)
  float* HIDF0 = (float*)ABUF;                   // head hidden (phase 6)
  float* HIDF1 = (float*)(ABUF + (size_t)15000 * 256 * 2);
  u16* PAD[5];                                   // padded bf16 input-linear A (phase 2)
  PAD[0] = ABUF;                       // atac0  25000*288 = 7.20M
  PAD[1] = ABUF +  7200000;            // gene0  15000*160 = 2.40M
  PAD[2] = ABUF +  9600000;            // pname0 12000*160 = 1.92M
  PAD[3] = ABUF + 11520000;            // atac1  25000*288 = 7.20M
  PAD[4] = ABUF + 18720000;            // gene1  15000*160 = 2.40M (ends 21.12M < 35.3M)

  long gbaseT[5];
  {
    long o = 0;
    for (int g = 0; g < 5; g++) { gbaseT[g] = o; o += (long)128 * GPITCH[g]; }
  }
  int* POSg[5];
  {
    int o = 0;
    for (int g = 0; g < 5; g++) { POSg[g] = POSB + o; o += NT[GD[g]]; }
  }

  // 1) weight prep + POS permutation
  {
    WTStackArgs wa{};
    int j = 0;
    for (int g = 0; g < 5; g++) {
      wa.gnr[g] = GNR[g];
      for (int i = 0; i < 6; i++) wa.grel[g][i] = GRELS[g][i];
      for (int s = 0; s <= GNR[g]; s++, j++) {
        wa.srcrel[j] = (s < GNR[g]) ? GRELS[g][s] : -1;
        wa.grp[j] = g;
        wa.outoff[j] = gbaseT[g];
        wa.koff[j] = s * 128;
        wa.pitch[j] = GPITCH[g];
      }
    }
    hipLaunchKernelGGL(wtstack_kernel, dim3(64, 23), dim3(256), 0, stream,
                       conv_wl, conv_wr, conv_bl, WTG, BLS, wa);
  }
  {
    WTArgs pa{};
    int s = 0;
    auto add = [&](const float* W, u16* o, int K, int N, int Kpad) {
      pa.W[s] = W; pa.out[s] = o; pa.K[s] = K; pa.N[s] = N; pa.Kpad[s] = Kpad; s++;
    };
    add(W_in_atac,  WTIA, 257, 128, 288);
    add(W_in_gene,  WTIG, 129, 128, 160);
    add(W_in_pname, WTIP, 129, 128, 160);
    for (int g = 0; g < 5; g++) {
      int d = GD[g];
      add(mlp_w1 + (long)d * 128 * 256, WTM1 + (long)g * 32768, 128, 256, 128);
      add(mlp_w2 + (long)d * 256 * 128, WTM2 + (long)g * 32768, 256, 128, 256);
    }
    add(gd_w1, WTHD, 128, 256, 128);
    add(gv_w1, WTHV, 128, 256, 128);
    hipLaunchKernelGGL(wt_kernel, dim3(144, 15), dim3(256), 0, stream, pa);
  }
  {
    PosArgs pa{};
    for (int g = 0; g < 5; g++) {
      int d = GD[g];
      pa.m0[g] = mapin(d, 0); pa.m1[g] = mapin(d, 1); pa.pos[g] = POSg[g]; pa.n[g] = NT[d];
    }
    hipLaunchKernelGGL(pos_kernel, dim3(98, 5), dim3(256), 0, stream, pa);
  }

  // 2) all fp32->bf16 converts in ONE launch + batched input-linear GEMMs
  {
    PadArgs pc{};
    auto addp = [&](int s, const float* src, u16* dst, int M, int K, int Kpad) {
      pc.src[s] = src; pc.dst[s] = dst; pc.K[s] = K;
      pc.Kpad8[s] = Kpad / 8; pc.total[s] = M * (Kpad / 8);
      pc.aligned[s] = ((K & 7) == 0) ? 1 : 0;
    };
    addp(0, xin(0,0), PAD[0], 25000, 257, 288);
    addp(1, xin(1,0), PAD[1], 15000, 129, 160);
    addp(2, xin(4,0), PAD[2], 12000, 129, 160);
    addp(3, xin(0,1), PAD[3], 25000, 257, 288);
    addp(4, xin(1,1), PAD[4], 15000, 129, 160);
    addp(5, xin(2,0), XB0[2],  4000, 128, 128);
    addp(6, xin(3,0), XB0[3], 12000, 128, 128);
    addp(7, xin(5,0), XB0[5], 15000, 128, 128);
    addp(8, xin(2,1), XB1[2],  4000, 128, 128);
    addp(9, xin(3,1), XB1[3], 12000, 128, 128);
    addp(10, xin(5,1), XB1[5], 15000, 128, 128);
    hipLaunchKernelGGL(padcvt_kernel, dim3(3516, 11), dim3(256), 0, stream, pc);

    InLinBArgs ia{};
    auto add = [&](int s, const u16* A, const u16* WT, const float* b, u16* C,
                   int M, int Kpad) {
      ia.A[s] = A; ia.WT[s] = WT; ia.bias[s] = b; ia.C[s] = C;
      ia.M[s] = M; ia.Kpad[s] = Kpad;
    };
    add(0, PAD[0], WTIA, b_in_atac,  XB0[0], 25000, 288);
    add(1, PAD[1], WTIG, b_in_gene,  XB0[1], 15000, 160);
    add(2, PAD[2], WTIP, b_in_pname, XB0[4], 12000, 160);
    add(3, PAD[3], WTIA, b_in_atac,  XB1[0], 25000, 288);
    add(4, PAD[4], WTIG, b_in_gene,  XB1[1], 15000, 160);
    hipLaunchKernelGGL(tgemm_inb, dim3(391, 1, 5), dim3(256), 0, stream, ia);
  }

  // 3) CSR build (combined L0 18 + L1 6 slots)
  static const int L0R[18] = {0,1,2,3,4,5,6,7,8,9,10,12,13,14,15,16,17,18};
  static const int L1R[6]  = {2, 4, 7, 9, 15, 17};
  int rpoffByRel[19], slotByRel[19], rpoff1[19], slot1[19];
  CsrArgs cc{};
  {
    int ro = 0, bo = 0, s = 0;
    for (int i = 0; i < 18; i++, s++) {
      int r = L0R[i];
      cc.relid[s] = r; cc.lay[s] = 0; int nd = NT[REL_D[r]];
      cc.nd[s] = nd; cc.rpoff[s] = ro;
      cc.bkoff[s] = bo; cc.bboff[s] = bo + s; cc.nb[s] = (nd + 127) >> 7;
      rpoffByRel[r] = ro; slotByRel[r] = s;
      ro += nd + 1; bo += cc.nb[s];
    }
    for (int i = 0; i < 6; i++, s++) {
      int r = L1R[i];
      cc.relid[s] = r; cc.lay[s] = 1;
      cc.nd[s] = 15000; cc.rpoff[s] = ro;
      cc.bkoff[s] = bo; cc.bboff[s] = bo + s; cc.nb[s] = (15000 + 127) >> 7;
      rpoff1[r] = ro; slot1[r] = s;
      ro += 15001; bo += cc.nb[s];
    }
    hipMemsetAsync(BCNT, 0, (size_t)bo * 4, stream);
    hipLaunchKernelGGL(bhist_kernel, dim3(24 * 25), dim3(256), 0, stream, edges0, edges1, BCNT, cc);
    hipLaunchKernelGGL(bscan_kernel, dim3(24), dim3(256), 0, stream, BCNT, BBASE, BCUR, cc);
    hipLaunchKernelGGL(bucket_scatter, dim3(24 * 25), dim3(256), 0, stream,
                       edges0, edges1, BCUR, TMP, cc);
    hipLaunchKernelGGL(bucket_to_csr, dim3(196, 24), dim3(256), 0, stream, TMP, BBASE, RP, ESRC, cc);
  }

  // 4) agg (18 gathered slots) -> fused conv+MLP1+MLP2+scatter (z=5)
  {
    AggAllArgs aa{};
    int j = 0;
    for (int g = 0; g < 5; g++) {
      int d = GD[g];
      for (int i = 0; i < GNR[g]; i++, j++) {
        int r = GRELS[g][i];
        aa.xsrc[j]   = XB0[REL_S[r]];
        aa.rowptr[j] = RP + rpoffByRel[r];
        aa.esrc[j]   = ESRC + (long)slotByRel[r] * E_EDGES;
        aa.dst[j] = ABUFg[g]; aa.nd[j] = NT[d]; aa.pitch[j] = GPA[g];
        aa.koff[j] = i * 128;
      }
    }
    hipLaunchKernelGGL(agg_all, dim3(1563, 18), dim3(256), 0, stream, aa);
  }
  {
    FusedArgs fa{};
    for (int g = 0; g < 5; g++) {
      int d = GD[g];
      fa.A[g] = ABUFg[g]; fa.selfA[g] = XB0[d];
      fa.WTC[g] = WTG + gbaseT[g]; fa.biasC[g] = BLS + g * 128;
      fa.W1[g] = WTM1 + (long)g * 32768; fa.b1[g] = mlp_b1 + d * 256;
      fa.W2[g] = WTM2 + (long)g * 32768; fa.b2[g] = mlp_b2 + d * 128;
      fa.POS[g] = POSg[g]; fa.C[g] = XB1[d];
      fa.M[g] = NT[d]; fa.kself[g] = GPA[g]; fa.Kpad[g] = GPITCH[g];
    }
    hipLaunchKernelGGL(fused_mlp, dim3(391, 1, 5), dim3(256), 0, stream, fa);
  }

  // 5) layer-1 gene conv: agg (6 slots) + conv (direct self) -> G1B (bf16)
  {
    AggAllArgs aa{};
    for (int i = 0; i < 6; i++) {
      int r = L1R[i];
      aa.xsrc[i]   = XB1[REL_S[r]];
      aa.rowptr[i] = RP + rpoff1[r];
      aa.esrc[i]   = ESRC + (long)slot1[r] * E_EDGES;
      aa.dst[i] = ABUF; aa.nd[i] = 15000; aa.pitch[i] = 768;
      aa.koff[i] = i * 128;
    }
    hipLaunchKernelGGL(agg_all, dim3(938, 6), dim3(256), 0, stream, aa);
    hipLaunchKernelGGL(conv_l1, dim3(235), dim3(256), 0, stream,
                       ABUF, XB1[1], WTG + gbaseT[1], BLS + 1 * 128, G1B,
                       15000, 768, 896);
  }

  // 6) gene heads: batched MFMA (z=2, bf16 A) + batched reduce
  {
    HeadArgs ha{};
    ha.WT[0] = WTHD; ha.WT[1] = WTHV;
    ha.b1[0] = gd_b1; ha.b1[1] = gv_b1;
    ha.hid[0] = HIDF0; ha.hid[1] = HIDF1;
    ha.A = G1B; ha.M = 15000;
    hipLaunchKernelGGL(tgemm_head, dim3(235, 2, 2), dim3(256), 0, stream, ha);
    HeadRArgs hr{};
    hr.hid[0] = HIDF0; hr.hid[1] = HIDF1;
    hr.w2[0] = gd_w2; hr.w2[1] = gv_w2;
    hr.b2[0] = gd_b2; hr.b2[1] = gv_b2;
    hr.out = out; hr.M = 15000;
    hipLaunchKernelGGL(head_reduce2, dim3(3750, 2), dim3(256), 0, stream, hr);
  }
}